// Round 2
// baseline (1054.937 us; speedup 1.0000x reference)
//
#include <hip/hip_runtime.h>
#include <hip/hip_bf16.h>
#include <math.h>

// GRU decoder: embed+relu -> gi GEMM -> batch-split GRU (no grid sync) ->
// vocab projection (bf16 MFMA, logits into d_out) -> in-place log_softmax.

typedef __bf16 bf16x8 __attribute__((ext_vector_type(8)));
typedef float  f32x4  __attribute__((ext_vector_type(4)));
typedef _Float16 f16x2 __attribute__((ext_vector_type(2)));
typedef unsigned short u16;
typedef u16 u16x8v __attribute__((ext_vector_type(8)));
typedef u16 u16x4v __attribute__((ext_vector_type(4)));
typedef unsigned u32x4v __attribute__((ext_vector_type(4)));

#define BTV (32L * 64 * 32000)

// ---- ws layout (bytes) ----
#define OFF_X    (0L)
#define SZ_X     (2048L * 256 * 2)
#define OFF_WIH  (OFF_X + SZ_X)
#define SZ_WIH   (1536L * 256 * 2)
#define OFF_WT   (OFF_WIH + SZ_WIH)
#define SZ_WT    (64L * 1536 * 4 * 4)      // packed f16-pair W_hh^T
#define OFF_WOUT (OFF_WT + SZ_WT)
#define SZ_WOUT  (32000L * 512 * 2)
#define OFF_GI   (OFF_WOUT + SZ_WOUT)
#define SZ_GI    (2048L * 1536 * 4)
#define OFF_HS   (OFF_GI + SZ_GI)
#define SZ_HS    (2048L * 512 * 2)
#define WS_NEED  (OFF_HS + SZ_HS)

__device__ __forceinline__ u16 f2bf(float f) {
  union { float f; unsigned u; } a; a.f = f;
  unsigned r = a.u + 0x7fffu + ((a.u >> 16) & 1u);
  return (u16)(r >> 16);
}

__device__ __forceinline__ unsigned packf16(float a, float b) {
  _Float16 x = (_Float16)a, y = (_Float16)b;
  return (unsigned)__builtin_bit_cast(unsigned short, x) |
         ((unsigned)__builtin_bit_cast(unsigned short, y) << 16);
}

__device__ __forceinline__ float dot2(unsigned w, unsigned h, float acc) {
#if __has_builtin(__builtin_amdgcn_fdot2)
  return __builtin_amdgcn_fdot2(__builtin_bit_cast(f16x2, w),
                                __builtin_bit_cast(f16x2, h), acc, false);
#else
  f16x2 a = __builtin_bit_cast(f16x2, w), b = __builtin_bit_cast(f16x2, h);
  return acc + (float)a.x * (float)b.x + (float)a.y * (float)b.y;
#endif
}

__device__ __forceinline__ void gload16(const void* g, void* l) {
  __builtin_amdgcn_global_load_lds(
      (const __attribute__((address_space(1))) unsigned int*)g,
      (__attribute__((address_space(3))) unsigned int*)l, 16, 0, 0);
}

// ---------------- cast f32 -> bf16 (grid-stride float4) ----------------
extern "C" __global__ void k_cast(const float* __restrict__ s, u16* __restrict__ d, int n4) {
  int i = blockIdx.x * blockDim.x + threadIdx.x;
  int st = gridDim.x * blockDim.x;
  for (; i < n4; i += st) {
    float4 v = reinterpret_cast<const float4*>(s)[i];
    u16x4v o; o.x = f2bf(v.x); o.y = f2bf(v.y); o.z = f2bf(v.z); o.w = f2bf(v.w);
    reinterpret_cast<u16x4v*>(d)[i] = o;
  }
}

// ---------------- W_hh [1536][512] f32 -> Wt[kq][1536 j][4] packed f16 pairs ----------------
// Wt[(kq*1536 + j)*4 + q] = pack(f16(W[j][8kq+2q]), f16(W[j][8kq+2q+1]))
extern "C" __global__ void k_wt(const float* __restrict__ W, unsigned* __restrict__ Wt) {
  int idx = blockIdx.x * 256 + threadIdx.x;  // 393216
  int q = idx & 3;
  int r = idx >> 2;
  int j = r % 1536;
  int kq = r / 1536;
  int k0 = kq * 8 + q * 2;
  const float* p = W + (long)j * 512 + k0;
  Wt[idx] = packf16(p[0], p[1]);
}

// ---------------- embed + relu -> X[t*32+b][256] bf16 ----------------
extern "C" __global__ void k_embed(const float* __restrict__ emb, const int* __restrict__ tgt,
                                   u16* __restrict__ X) {
  int idx = blockIdx.x * 256 + threadIdx.x;  // 65536 total
  int row = idx >> 5;                        // 0..2047  (= t*32 + b)
  int c8  = (idx & 31) << 3;
  int t = row >> 5, b = row & 31;
  int token = (t == 0) ? 0 : tgt[b * 64 + t - 1];
  const float* e = emb + (long)token * 256 + c8;
  u16x8v o;
#pragma unroll
  for (int i = 0; i < 8; ++i) { float v = e[i]; o[i] = f2bf(v > 0.f ? v : 0.f); }
  *reinterpret_cast<u16x8v*>(X + (long)row * 256 + c8) = o;
}

// ---------------- generic bf16 MFMA GEMM, C = A*B^T + bias ----------------
extern "C" __global__ void __launch_bounds__(256)
k_gemm_bt(const u16* __restrict__ A, const u16* __restrict__ B,
          const float* __restrict__ bias, float* __restrict__ C,
          int M, int N, int K) {
  __shared__ u16 At[128 * 32];
  __shared__ u16 Bt[128 * 32];
  int mt = M >> 7;
  int bn = blockIdx.x / mt, bm = blockIdx.x % mt;
  int tid = threadIdx.x, wave = tid >> 6, lane = tid & 63;
  int wr = wave >> 1, wc = wave & 1;
  f32x4 acc[4][4] = {};
  const u16* ga = A + (long)(bm * 128 + wave * 32 + (lane >> 2)) * K + ((lane & 3) << 3);
  const u16* gb = B + (long)(bn * 128 + wave * 32 + (lane >> 2)) * K + ((lane & 3) << 3);
  u16* la0 = &At[wave * 1024]; u16* la1 = la0 + 512;
  u16* lb0 = &Bt[wave * 1024]; u16* lb1 = lb0 + 512;
  long k16 = 16L * K;
  for (int k0 = 0; k0 < K; k0 += 32) {
    if (k0) __syncthreads();
    gload16(ga + k0, la0);
    gload16(ga + k16 + k0, la1);
    gload16(gb + k0, lb0);
    gload16(gb + k16 + k0, lb1);
    __syncthreads();
    bf16x8 af[4], bfr[4];
#pragma unroll
    for (int mi = 0; mi < 4; ++mi)
      af[mi] = *reinterpret_cast<const bf16x8*>(
          &At[(wr * 64 + mi * 16 + (lane & 15)) * 32 + ((lane >> 4) << 3)]);
#pragma unroll
    for (int ni = 0; ni < 4; ++ni)
      bfr[ni] = *reinterpret_cast<const bf16x8*>(
          &Bt[(wc * 64 + ni * 16 + (lane & 15)) * 32 + ((lane >> 4) << 3)]);
#pragma unroll
    for (int mi = 0; mi < 4; ++mi)
#pragma unroll
      for (int ni = 0; ni < 4; ++ni)
        acc[mi][ni] = __builtin_amdgcn_mfma_f32_16x16x32_bf16(af[mi], bfr[ni], acc[mi][ni], 0, 0, 0);
  }
  int rb = bm * 128 + wr * 64 + ((lane >> 4) << 2);
  int cb = bn * 128 + wc * 64 + (lane & 15);
#pragma unroll
  for (int mi = 0; mi < 4; ++mi)
#pragma unroll
    for (int ni = 0; ni < 4; ++ni) {
      int col = cb + ni * 16;
      float bv = bias[col];
#pragma unroll
      for (int q = 0; q < 4; ++q) {
        int rr = rb + mi * 16 + q;
        C[(long)rr * N + col] = acc[mi][ni][q] + bv;
      }
    }
}

// ---------------- batch-split GRU: 32 blocks x 512 thr, NO grid sync ----------------
// Block b owns batch row b. h lives in LDS (f32 + packed f16 pairs).
// Thread tid computes gates r,z,n for hidden unit j=tid via f16 dot2 GEMV.
extern "C" __global__ void __launch_bounds__(512)
k_gru2(const float* __restrict__ gi, const unsigned* __restrict__ Wt,
       const float* __restrict__ bhh, const float* __restrict__ eh,
       u16* __restrict__ HS, float* __restrict__ outH) {
  __shared__ float hf[512];
  __shared__ unsigned hp[256];
  int b = blockIdx.x, tid = threadIdx.x;
  float h0 = eh[b * 512 + tid];
  hf[tid] = h0;
  float oth0 = __shfl_xor(h0, 1, 64);
  if (!(tid & 1)) hp[tid >> 1] = packf16(h0, oth0);
  float b0 = bhh[tid], b1 = bhh[512 + tid], b2 = bhh[1024 + tid];
  const unsigned* w0b = Wt + (long)tid * 4;
  const unsigned* w1b = Wt + (long)(tid + 512) * 4;
  const unsigned* w2b = Wt + (long)(tid + 1024) * 4;
  __syncthreads();
  for (int t = 0; t < 64; ++t) {
    float a0[2] = {0.f, 0.f}, a1[2] = {0.f, 0.f}, a2[2] = {0.f, 0.f};
#pragma unroll 4
    for (int kq = 0; kq < 64; ++kq) {
      u32x4v hh = *reinterpret_cast<const u32x4v*>(&hp[kq * 4]);
      u32x4v w0 = *reinterpret_cast<const u32x4v*>(w0b + (long)kq * 6144);
      u32x4v w1 = *reinterpret_cast<const u32x4v*>(w1b + (long)kq * 6144);
      u32x4v w2 = *reinterpret_cast<const u32x4v*>(w2b + (long)kq * 6144);
#pragma unroll
      for (int q = 0; q < 4; ++q) {
        a0[q & 1] = dot2(w0[q], hh[q], a0[q & 1]);
        a1[q & 1] = dot2(w1[q], hh[q], a1[q & 1]);
        a2[q & 1] = dot2(w2[q], hh[q], a2[q & 1]);
      }
    }
    float hr = a0[0] + a0[1] + b0;
    float hz = a1[0] + a1[1] + b1;
    float hn = a2[0] + a2[1] + b2;
    const float* gib = gi + ((long)t * 32 + b) * 1536;
    float ir = gib[tid], iz = gib[512 + tid], inn = gib[1024 + tid];
    float r = 1.f / (1.f + __expf(-(ir + hr)));
    float z = 1.f / (1.f + __expf(-(iz + hz)));
    float x = inn + r * hn;
    float ax = fabsf(x), ee = __expf(-2.f * ax);
    float th = (1.f - ee) / (1.f + ee);
    th = x < 0.f ? -th : th;
    float hprev = hf[tid];
    float hnew = (1.f - z) * th + z * hprev;
    __syncthreads();   // all dot-reads of hp/hf for step t done
    hf[tid] = hnew;
    float oth = __shfl_xor(hnew, 1, 64);
    if (!(tid & 1)) hp[tid >> 1] = packf16(hnew, oth);
    HS[((long)b * 64 + t) * 512 + tid] = f2bf(hnew);
    if (t == 63) outH[b * 512 + tid] = hnew;
    __syncthreads();   // h state ready for step t+1
  }
}

// ---------------- in-place log_softmax over rows of 32000 ----------------
extern "C" __global__ void __launch_bounds__(512)
k_lsm(float* __restrict__ P) {
  extern __shared__ float sr[];
  __shared__ float red[8];
  long base = (long)blockIdx.x * 32000;
  int tid = threadIdx.x, wave = tid >> 6, lane = tid & 63;
  float mx = -INFINITY;
  for (int i = tid; i < 8000; i += 512) {
    float4 v = reinterpret_cast<const float4*>(P + base)[i];
    reinterpret_cast<float4*>(sr)[i] = v;
    mx = fmaxf(mx, fmaxf(fmaxf(v.x, v.y), fmaxf(v.z, v.w)));
  }
#pragma unroll
  for (int off = 32; off; off >>= 1) mx = fmaxf(mx, __shfl_down(mx, off, 64));
  if (lane == 0) red[wave] = mx;
  __syncthreads();
  if (tid == 0) {
    float m = red[0];
#pragma unroll
    for (int w = 1; w < 8; ++w) m = fmaxf(m, red[w]);
    red[0] = m;
  }
  __syncthreads();
  mx = red[0];
  __syncthreads();
  float sm = 0.f;
  for (int i = tid; i < 8000; i += 512) {
    float4 v = reinterpret_cast<const float4*>(sr)[i];
    sm += __expf(v.x - mx) + __expf(v.y - mx) + __expf(v.z - mx) + __expf(v.w - mx);
  }
#pragma unroll
  for (int off = 32; off; off >>= 1) sm += __shfl_down(sm, off, 64);
  if (lane == 0) red[wave] = sm;
  __syncthreads();
  if (tid == 0) {
    float s = 0.f;
#pragma unroll
    for (int w = 0; w < 8; ++w) s += red[w];
    red[0] = mx + __logf(s);
  }
  __syncthreads();
  float L = red[0];
  for (int i = tid; i < 8000; i += 512) {
    float4 v = reinterpret_cast<const float4*>(sr)[i];
    v.x -= L; v.y -= L; v.z -= L; v.w -= L;
    reinterpret_cast<float4*>(P + base)[i] = v;
  }
}

extern "C" void kernel_launch(void* const* d_in, const int* in_sizes, int n_in,
                              void* d_out, int out_size, void* d_ws, size_t ws_size,
                              hipStream_t stream) {
  (void)in_sizes; (void)n_in; (void)out_size;
  const float* enc_hid = (const float*)d_in[1];
  const int*   tgt     = (const int*)d_in[2];
  const float* emb     = (const float*)d_in[3];
  const float* W_ih    = (const float*)d_in[4];
  const float* W_hh    = (const float*)d_in[5];
  const float* b_ih    = (const float*)d_in[6];
  const float* b_hh    = (const float*)d_in[7];
  const float* W_out   = (const float*)d_in[8];
  const float* b_out   = (const float*)d_in[9];
  float* out = (float*)d_out;
  char* ws = (char*)d_ws;
  if (ws_size < (size_t)WS_NEED) return;

  u16* X        = (u16*)(ws + OFF_X);
  u16* Wih      = (u16*)(ws + OFF_WIH);
  unsigned* Wt  = (unsigned*)(ws + OFF_WT);
  u16* Wout     = (u16*)(ws + OFF_WOUT);
  float* gi     = (float*)(ws + OFF_GI);
  u16* HS       = (u16*)(ws + OFF_HS);

  hipFuncSetAttribute(reinterpret_cast<const void*>(k_lsm),
                      hipFuncAttributeMaxDynamicSharedMemorySize, 131072);

  k_cast<<<96, 256, 0, stream>>>(W_ih, Wih, 1536 * 256 / 4);
  k_cast<<<2048, 256, 0, stream>>>(W_out, Wout, 32000 * 512 / 4);
  k_wt<<<1536, 256, 0, stream>>>(W_hh, Wt);
  k_embed<<<256, 256, 0, stream>>>(emb, tgt, X);
  k_gemm_bt<<<(1536 / 128) * (2048 / 128), 256, 0, stream>>>(X, Wih, b_ih, gi, 2048, 1536, 256);
  k_gru2<<<32, 512, 0, stream>>>(gi, Wt, b_hh, enc_hid, HS, out + BTV);
  k_gemm_bt<<<(32000 / 128) * (2048 / 128), 256, 0, stream>>>(HS, Wout, b_out, out, 2048, 32000, 512);
  k_lsm<<<2048, 512, 128000, stream>>>(out);
}

// Round 3
// 747.826 us; speedup vs baseline: 1.4107x; 1.4107x over previous
//
#include <hip/hip_runtime.h>
#include <hip/hip_bf16.h>
#include <math.h>

// GRU decoder: embed+relu -> gi GEMM -> hidden-split GRU (flag barrier, W in VGPRs)
// -> vocab projection (bf16 MFMA, logits into d_out) -> in-place log_softmax.

typedef __bf16 bf16x8 __attribute__((ext_vector_type(8)));
typedef float  f32x4  __attribute__((ext_vector_type(4)));
typedef unsigned short u16;
typedef u16 u16x8v __attribute__((ext_vector_type(8)));
typedef u16 u16x4v __attribute__((ext_vector_type(4)));

#define BTV (32L * 64 * 32000)

// ---- ws layout (bytes) ----
#define OFF_X    (0L)
#define SZ_X     (2048L * 256 * 2)
#define OFF_WIH  (OFF_X + SZ_X)
#define SZ_WIH   (1536L * 256 * 2)
#define OFF_WHH  (OFF_WIH + SZ_WIH)
#define SZ_WHH   (1536L * 512 * 2)
#define OFF_WOUT (OFF_WHH + SZ_WHH)
#define SZ_WOUT  (32000L * 512 * 2)
#define OFF_GI   (OFF_WOUT + SZ_WOUT)
#define SZ_GI    (2048L * 1536 * 4)
#define OFF_HS   (OFF_GI + SZ_GI)
#define SZ_HS    (2048L * 512 * 2)
#define OFF_HB   (OFF_HS + SZ_HS)
#define SZ_HB    (2L * 32 * 512 * 2)
#define OFF_FLG  (OFF_HB + SZ_HB)
#define SZ_FLG   (256L)
#define WS_NEED  (OFF_FLG + SZ_FLG)

__device__ __forceinline__ u16 f2bf(float f) {
  union { float f; unsigned u; } a; a.f = f;
  unsigned r = a.u + 0x7fffu + ((a.u >> 16) & 1u);
  return (u16)(r >> 16);
}

__device__ __forceinline__ void gload16(const void* g, void* l) {
  __builtin_amdgcn_global_load_lds(
      (const __attribute__((address_space(1))) unsigned int*)g,
      (__attribute__((address_space(3))) unsigned int*)l, 16, 0, 0);
}

// ---------------- cast f32 -> bf16 (grid-stride float4) ----------------
extern "C" __global__ void k_cast(const float* __restrict__ s, u16* __restrict__ d, int n4) {
  int i = blockIdx.x * blockDim.x + threadIdx.x;
  int st = gridDim.x * blockDim.x;
  for (; i < n4; i += st) {
    float4 v = reinterpret_cast<const float4*>(s)[i];
    u16x4v o; o.x = f2bf(v.x); o.y = f2bf(v.y); o.z = f2bf(v.z); o.w = f2bf(v.w);
    reinterpret_cast<u16x4v*>(d)[i] = o;
  }
}

// ---------------- embed + relu -> X[t*32+b][256] bf16 ----------------
extern "C" __global__ void k_embed(const float* __restrict__ emb, const int* __restrict__ tgt,
                                   u16* __restrict__ X) {
  int idx = blockIdx.x * 256 + threadIdx.x;  // 65536 total
  int row = idx >> 5;                        // 0..2047  (= t*32 + b)
  int c8  = (idx & 31) << 3;
  int t = row >> 5, b = row & 31;
  int token = (t == 0) ? 0 : tgt[b * 64 + t - 1];
  const float* e = emb + (long)token * 256 + c8;
  u16x8v o;
#pragma unroll
  for (int i = 0; i < 8; ++i) { float v = e[i]; o[i] = f2bf(v > 0.f ? v : 0.f); }
  *reinterpret_cast<u16x8v*>(X + (long)row * 256 + c8) = o;
}

// ---------------- h0 (bf16) + flags init ----------------
extern "C" __global__ void k_init(const float* __restrict__ eh, u16* __restrict__ Hb,
                                  unsigned* __restrict__ flags) {
  int i = blockIdx.x * 256 + threadIdx.x;  // 16384
  Hb[i] = f2bf(eh[i]);
  if (i < 64) flags[i] = 0u;
}

// ---------------- generic bf16 MFMA GEMM, C = A*B^T + bias ----------------
extern "C" __global__ void __launch_bounds__(256)
k_gemm_bt(const u16* __restrict__ A, const u16* __restrict__ B,
          const float* __restrict__ bias, float* __restrict__ C,
          int M, int N, int K) {
  __shared__ u16 At[128 * 32];
  __shared__ u16 Bt[128 * 32];
  int mt = M >> 7;
  int bn = blockIdx.x / mt, bm = blockIdx.x % mt;
  int tid = threadIdx.x, wave = tid >> 6, lane = tid & 63;
  int wr = wave >> 1, wc = wave & 1;
  f32x4 acc[4][4] = {};
  const u16* ga = A + (long)(bm * 128 + wave * 32 + (lane >> 2)) * K + ((lane & 3) << 3);
  const u16* gb = B + (long)(bn * 128 + wave * 32 + (lane >> 2)) * K + ((lane & 3) << 3);
  u16* la0 = &At[wave * 1024]; u16* la1 = la0 + 512;
  u16* lb0 = &Bt[wave * 1024]; u16* lb1 = lb0 + 512;
  long k16 = 16L * K;
  for (int k0 = 0; k0 < K; k0 += 32) {
    if (k0) __syncthreads();
    gload16(ga + k0, la0);
    gload16(ga + k16 + k0, la1);
    gload16(gb + k0, lb0);
    gload16(gb + k16 + k0, lb1);
    __syncthreads();
    bf16x8 af[4], bfr[4];
#pragma unroll
    for (int mi = 0; mi < 4; ++mi)
      af[mi] = *reinterpret_cast<const bf16x8*>(
          &At[(wr * 64 + mi * 16 + (lane & 15)) * 32 + ((lane >> 4) << 3)]);
#pragma unroll
    for (int ni = 0; ni < 4; ++ni)
      bfr[ni] = *reinterpret_cast<const bf16x8*>(
          &Bt[(wc * 64 + ni * 16 + (lane & 15)) * 32 + ((lane >> 4) << 3)]);
#pragma unroll
    for (int mi = 0; mi < 4; ++mi)
#pragma unroll
      for (int ni = 0; ni < 4; ++ni)
        acc[mi][ni] = __builtin_amdgcn_mfma_f32_16x16x32_bf16(af[mi], bfr[ni], acc[mi][ni], 0, 0, 0);
  }
  int rb = bm * 128 + wr * 64 + ((lane >> 4) << 2);
  int cb = bn * 128 + wc * 64 + (lane & 15);
#pragma unroll
  for (int mi = 0; mi < 4; ++mi)
#pragma unroll
    for (int ni = 0; ni < 4; ++ni) {
      int col = cb + ni * 16;
      float bv = bias[col];
#pragma unroll
      for (int q = 0; q < 4; ++q) {
        int rr = rb + mi * 16 + q;
        C[(long)rr * N + col] = acc[mi][ni][q] + bv;
      }
    }
}

// ---------------- hidden-split GRU: 32 blocks x 192 thr (wave = gate) ----------------
// Block g owns hidden units j in [16g, 16g+16). W slice lives in VGPRs across all 64
// steps. Per step: stage h (32KB, XOR-swizzled) into LDS, 32 MFMAs/wave, gate
// exchange via LDS, elementwise update, flag-store + wave-parallel poll barrier.
extern "C" __global__ void __launch_bounds__(192, 1)
k_gru3(const float* __restrict__ gi, const u16* __restrict__ Whh,
       const float* __restrict__ bhh, const float* __restrict__ eh,
       u16* __restrict__ Hb, u16* __restrict__ HS, float* __restrict__ outH,
       unsigned* __restrict__ flags) {
  __shared__ u16 Asm[32 * 512];        // swizzled h tile (32 KB)
  __shared__ float gh[3][32][17];
  int g = blockIdx.x, tid = threadIdx.x, wave = tid >> 6, lane = tid & 63;
  int j0 = g * 16;
  // B fragments (this wave's gate rows) in registers, all 512 k.
  bf16x8 barr[16];
  {
    const u16* wrow = Whh + (long)(wave * 512 + j0 + (lane & 15)) * 512 + ((lane >> 4) << 3);
#pragma unroll
    for (int kk = 0; kk < 16; ++kk)
      barr[kk] = *reinterpret_cast<const bf16x8*>(wrow + kk * 32);
  }
  // per-thread output slots: o = s*192 + tid over 512 outputs (b = o>>4, u = o&15)
  float hprev[3] = {0.f, 0.f, 0.f}, bb0[3], bb1[3], bb2[3];
#pragma unroll
  for (int s = 0; s < 3; ++s) {
    int o = s * 192 + tid;
    if (o < 512) {
      int b = o >> 4, u = o & 15, j = j0 + u;
      hprev[s] = eh[b * 512 + j];
      bb0[s] = bhh[j]; bb1[s] = bhh[512 + j]; bb2[s] = bhh[1024 + j];
    }
  }
  for (int t = 0; t < 64; ++t) {
    int cur = t & 1, nxt = cur ^ 1;
    const u16* hsrc = Hb + cur * 16384;
    // gi prefetch (independent of h) before the barrier poll
    float gr[3], gz[3], gn[3];
#pragma unroll
    for (int s = 0; s < 3; ++s) {
      int o = s * 192 + tid;
      if (o < 512) {
        int b = o >> 4, u = o & 15, j = j0 + u;
        const float* gp = gi + ((long)t * 32 + b) * 1536;
        gr[s] = gp[j]; gz[s] = gp[512 + j]; gn[s] = gp[1024 + j];
      }
    }
    if (t) {
      if (wave == 0) {
        unsigned ph = (unsigned)t;
        while (__hip_atomic_load(&flags[lane & 31], __ATOMIC_ACQUIRE,
                                 __HIP_MEMORY_SCOPE_AGENT) < ph) { }
      }
      __syncthreads();
      __threadfence();   // acquire: invalidate stale L1/L2 before reading Hb
    }
    // stage h -> LDS, swizzled: LDS[row*1024 + (kbyte ^ ((row&15)<<6))] = Hb[row][kbyte]
    // (inverse-swizzle applied on the global source; LDS dest linear)
#pragma unroll
    for (int it = 0; it < 11; ++it) {
      int cbase = it * 192 + wave * 64;
      if (cbase < 2048) {
        int row = cbase >> 6;
        int kb = ((lane & 63) << 4) ^ ((row & 15) << 6);
        gload16(hsrc + row * 512 + (kb >> 1), (char*)Asm + cbase * 16);
      }
    }
    asm volatile("s_waitcnt vmcnt(0)" ::: "memory");
    __syncthreads();
    // MFMA: this wave's gate, C[32 b x 16 u] as two 16x16 m-tiles
    f32x4 acc0 = {}, acc1 = {};
    int r15 = lane & 15;
#pragma unroll
    for (int kk = 0; kk < 16; ++kk) {
      int sw = ((kk << 6) + ((lane >> 4) << 4)) ^ (r15 << 6);
      bf16x8 a0 = *reinterpret_cast<const bf16x8*>((const char*)Asm + r15 * 1024 + sw);
      bf16x8 a1 = *reinterpret_cast<const bf16x8*>((const char*)Asm + (16 + r15) * 1024 + sw);
      acc0 = __builtin_amdgcn_mfma_f32_16x16x32_bf16(a0, barr[kk], acc0, 0, 0, 0);
      acc1 = __builtin_amdgcn_mfma_f32_16x16x32_bf16(a1, barr[kk], acc1, 0, 0, 0);
    }
#pragma unroll
    for (int q = 0; q < 4; ++q) {
      int r0 = ((lane >> 4) << 2) + q;
      gh[wave][r0][r15] = acc0[q];
      gh[wave][16 + r0][r15] = acc1[q];
    }
    __syncthreads();
    // elementwise gate math + state update
#pragma unroll
    for (int s = 0; s < 3; ++s) {
      int o = s * 192 + tid;
      if (o < 512) {
        int b = o >> 4, u = o & 15, j = j0 + u;
        float hr = gh[0][b][u] + bb0[s];
        float hz = gh[1][b][u] + bb1[s];
        float hn = gh[2][b][u] + bb2[s];
        float r = 1.f / (1.f + __expf(-(gr[s] + hr)));
        float z = 1.f / (1.f + __expf(-(gz[s] + hz)));
        float x = gn[s] + r * hn;
        float ax = fabsf(x), ee = __expf(-2.f * ax);
        float th = (1.f - ee) / (1.f + ee);
        th = x < 0.f ? -th : th;
        float hnew = (1.f - z) * th + z * hprev[s];
        hprev[s] = hnew;
        u16 hb = f2bf(hnew);
        Hb[nxt * 16384 + b * 512 + j] = hb;
        HS[((long)b * 64 + t) * 512 + j] = hb;
        if (t == 63) outH[b * 512 + j] = hnew;
      }
    }
    __threadfence();     // release: drain + write back this wave's stores
    __syncthreads();
    if (tid == 0)
      __hip_atomic_store(&flags[g], (unsigned)(t + 1), __ATOMIC_RELEASE,
                         __HIP_MEMORY_SCOPE_AGENT);
  }
}

// ---------------- in-place log_softmax over rows of 32000 ----------------
extern "C" __global__ void __launch_bounds__(512)
k_lsm(float* __restrict__ P) {
  extern __shared__ float sr[];
  __shared__ float red[8];
  long base = (long)blockIdx.x * 32000;
  int tid = threadIdx.x, wave = tid >> 6, lane = tid & 63;
  float mx = -INFINITY;
  for (int i = tid; i < 8000; i += 512) {
    float4 v = reinterpret_cast<const float4*>(P + base)[i];
    reinterpret_cast<float4*>(sr)[i] = v;
    mx = fmaxf(mx, fmaxf(fmaxf(v.x, v.y), fmaxf(v.z, v.w)));
  }
#pragma unroll
  for (int off = 32; off; off >>= 1) mx = fmaxf(mx, __shfl_down(mx, off, 64));
  if (lane == 0) red[wave] = mx;
  __syncthreads();
  if (tid == 0) {
    float m = red[0];
#pragma unroll
    for (int w = 1; w < 8; ++w) m = fmaxf(m, red[w]);
    red[0] = m;
  }
  __syncthreads();
  mx = red[0];
  __syncthreads();
  float sm = 0.f;
  for (int i = tid; i < 8000; i += 512) {
    float4 v = reinterpret_cast<const float4*>(sr)[i];
    sm += __expf(v.x - mx) + __expf(v.y - mx) + __expf(v.z - mx) + __expf(v.w - mx);
  }
#pragma unroll
  for (int off = 32; off; off >>= 1) sm += __shfl_down(sm, off, 64);
  if (lane == 0) red[wave] = sm;
  __syncthreads();
  if (tid == 0) {
    float s = 0.f;
#pragma unroll
    for (int w = 0; w < 8; ++w) s += red[w];
    red[0] = mx + __logf(s);
  }
  __syncthreads();
  float L = red[0];
  for (int i = tid; i < 8000; i += 512) {
    float4 v = reinterpret_cast<const float4*>(sr)[i];
    v.x -= L; v.y -= L; v.z -= L; v.w -= L;
    reinterpret_cast<float4*>(P + base)[i] = v;
  }
}

extern "C" void kernel_launch(void* const* d_in, const int* in_sizes, int n_in,
                              void* d_out, int out_size, void* d_ws, size_t ws_size,
                              hipStream_t stream) {
  (void)in_sizes; (void)n_in; (void)out_size;
  const float* enc_hid = (const float*)d_in[1];
  const int*   tgt     = (const int*)d_in[2];
  const float* emb     = (const float*)d_in[3];
  const float* W_ih    = (const float*)d_in[4];
  const float* W_hh    = (const float*)d_in[5];
  const float* b_ih    = (const float*)d_in[6];
  const float* b_hh    = (const float*)d_in[7];
  const float* W_out   = (const float*)d_in[8];
  const float* b_out   = (const float*)d_in[9];
  float* out = (float*)d_out;
  char* ws = (char*)d_ws;
  if (ws_size < (size_t)WS_NEED) return;

  u16* X        = (u16*)(ws + OFF_X);
  u16* Wih      = (u16*)(ws + OFF_WIH);
  u16* Whh      = (u16*)(ws + OFF_WHH);
  u16* Wout     = (u16*)(ws + OFF_WOUT);
  float* gi     = (float*)(ws + OFF_GI);
  u16* HS       = (u16*)(ws + OFF_HS);
  u16* Hb       = (u16*)(ws + OFF_HB);
  unsigned* flg = (unsigned*)(ws + OFF_FLG);

  hipFuncSetAttribute(reinterpret_cast<const void*>(k_lsm),
                      hipFuncAttributeMaxDynamicSharedMemorySize, 131072);

  k_cast<<<96, 256, 0, stream>>>(W_ih, Wih, 1536 * 256 / 4);
  k_cast<<<192, 256, 0, stream>>>(W_hh, Whh, 1536 * 512 / 4);
  k_cast<<<2048, 256, 0, stream>>>(W_out, Wout, 32000 * 512 / 4);
  k_embed<<<256, 256, 0, stream>>>(emb, tgt, X);
  k_init<<<64, 256, 0, stream>>>(enc_hid, Hb, flg);
  k_gemm_bt<<<(1536 / 128) * (2048 / 128), 256, 0, stream>>>(X, Wih, b_ih, gi, 2048, 1536, 256);
  k_gru3<<<32, 192, 0, stream>>>(gi, Whh, b_hh, enc_hid, Hb, HS, out + BTV, flg);
  k_gemm_bt<<<(32000 / 128) * (2048 / 128), 256, 0, stream>>>(HS, Wout, b_out, out, 2048, 32000, 512);
  k_lsm<<<2048, 512, 128000, stream>>>(out);
}

// Round 4
// 589.504 us; speedup vs baseline: 1.7895x; 1.2686x over previous
//
#include <hip/hip_runtime.h>
#include <hip/hip_bf16.h>
#include <math.h>

// GRU decoder: embed+relu -> gi GEMM -> hidden-split GRU (8 blocks, coherent-store
// flag barrier, W in VGPRs) -> vocab projection (bf16 MFMA) -> in-place log_softmax.

typedef __bf16 bf16x8 __attribute__((ext_vector_type(8)));
typedef float  f32x4  __attribute__((ext_vector_type(4)));
typedef unsigned short u16;
typedef u16 u16x8v __attribute__((ext_vector_type(8)));
typedef u16 u16x4v __attribute__((ext_vector_type(4)));

#define BTV (32L * 64 * 32000)

// ---- ws layout (bytes) ----
#define OFF_X    (0L)
#define SZ_X     (2048L * 256 * 2)
#define OFF_WIH  (OFF_X + SZ_X)
#define SZ_WIH   (1536L * 256 * 2)
#define OFF_WHH  (OFF_WIH + SZ_WIH)
#define SZ_WHH   (1536L * 512 * 2)
#define OFF_WOUT (OFF_WHH + SZ_WHH)
#define SZ_WOUT  (32000L * 512 * 2)
#define OFF_GI   (OFF_WOUT + SZ_WOUT)
#define SZ_GI    (2048L * 1536 * 4)
#define OFF_HS   (OFF_GI + SZ_GI)
#define SZ_HS    (2048L * 512 * 2)
#define OFF_HB   (OFF_HS + SZ_HS)
#define SZ_HB    (2L * 32 * 512 * 2)
#define OFF_FLG  (OFF_HB + SZ_HB)
#define SZ_FLG   (512L)
#define WS_NEED  (OFF_FLG + SZ_FLG)

__device__ __forceinline__ u16 f2bf(float f) {
  union { float f; unsigned u; } a; a.f = f;
  unsigned r = a.u + 0x7fffu + ((a.u >> 16) & 1u);
  return (u16)(r >> 16);
}

__device__ __forceinline__ void gload16(const void* g, void* l) {
  __builtin_amdgcn_global_load_lds(
      (const __attribute__((address_space(1))) unsigned int*)g,
      (__attribute__((address_space(3))) unsigned int*)l, 16, 0, 0);
}

// ---------------- cast f32 -> bf16 (grid-stride float4) ----------------
extern "C" __global__ void k_cast(const float* __restrict__ s, u16* __restrict__ d, int n4) {
  int i = blockIdx.x * blockDim.x + threadIdx.x;
  int st = gridDim.x * blockDim.x;
  for (; i < n4; i += st) {
    float4 v = reinterpret_cast<const float4*>(s)[i];
    u16x4v o; o.x = f2bf(v.x); o.y = f2bf(v.y); o.z = f2bf(v.z); o.w = f2bf(v.w);
    reinterpret_cast<u16x4v*>(d)[i] = o;
  }
}

// ---------------- embed + relu -> X[t*32+b][256] bf16 ----------------
extern "C" __global__ void k_embed(const float* __restrict__ emb, const int* __restrict__ tgt,
                                   u16* __restrict__ X) {
  int idx = blockIdx.x * 256 + threadIdx.x;  // 65536 total
  int row = idx >> 5;                        // 0..2047  (= t*32 + b)
  int c8  = (idx & 31) << 3;
  int t = row >> 5, b = row & 31;
  int token = (t == 0) ? 0 : tgt[b * 64 + t - 1];
  const float* e = emb + (long)token * 256 + c8;
  u16x8v o;
#pragma unroll
  for (int i = 0; i < 8; ++i) { float v = e[i]; o[i] = f2bf(v > 0.f ? v : 0.f); }
  *reinterpret_cast<u16x8v*>(X + (long)row * 256 + c8) = o;
}

// ---------------- h0 (bf16) + flags init ----------------
extern "C" __global__ void k_init(const float* __restrict__ eh, u16* __restrict__ Hb,
                                  unsigned* __restrict__ flags) {
  int i = blockIdx.x * 256 + threadIdx.x;  // 16384
  Hb[i] = f2bf(eh[i]);
  if (i < 128) flags[i] = 0u;
}

// ---------------- generic bf16 MFMA GEMM, C = A*B^T + bias ----------------
extern "C" __global__ void __launch_bounds__(256)
k_gemm_bt(const u16* __restrict__ A, const u16* __restrict__ B,
          const float* __restrict__ bias, float* __restrict__ C,
          int M, int N, int K) {
  __shared__ u16 At[128 * 32];
  __shared__ u16 Bt[128 * 32];
  int mt = M >> 7;
  int bn = blockIdx.x / mt, bm = blockIdx.x % mt;
  int tid = threadIdx.x, wave = tid >> 6, lane = tid & 63;
  int wr = wave >> 1, wc = wave & 1;
  f32x4 acc[4][4] = {};
  const u16* ga = A + (long)(bm * 128 + wave * 32 + (lane >> 2)) * K + ((lane & 3) << 3);
  const u16* gb = B + (long)(bn * 128 + wave * 32 + (lane >> 2)) * K + ((lane & 3) << 3);
  u16* la0 = &At[wave * 1024]; u16* la1 = la0 + 512;
  u16* lb0 = &Bt[wave * 1024]; u16* lb1 = lb0 + 512;
  long k16 = 16L * K;
  for (int k0 = 0; k0 < K; k0 += 32) {
    if (k0) __syncthreads();
    gload16(ga + k0, la0);
    gload16(ga + k16 + k0, la1);
    gload16(gb + k0, lb0);
    gload16(gb + k16 + k0, lb1);
    __syncthreads();
    bf16x8 af[4], bfr[4];
#pragma unroll
    for (int mi = 0; mi < 4; ++mi)
      af[mi] = *reinterpret_cast<const bf16x8*>(
          &At[(wr * 64 + mi * 16 + (lane & 15)) * 32 + ((lane >> 4) << 3)]);
#pragma unroll
    for (int ni = 0; ni < 4; ++ni)
      bfr[ni] = *reinterpret_cast<const bf16x8*>(
          &Bt[(wc * 64 + ni * 16 + (lane & 15)) * 32 + ((lane >> 4) << 3)]);
#pragma unroll
    for (int mi = 0; mi < 4; ++mi)
#pragma unroll
      for (int ni = 0; ni < 4; ++ni)
        acc[mi][ni] = __builtin_amdgcn_mfma_f32_16x16x32_bf16(af[mi], bfr[ni], acc[mi][ni], 0, 0, 0);
  }
  int rb = bm * 128 + wr * 64 + ((lane >> 4) << 2);
  int cb = bn * 128 + wc * 64 + (lane & 15);
#pragma unroll
  for (int mi = 0; mi < 4; ++mi)
#pragma unroll
    for (int ni = 0; ni < 4; ++ni) {
      int col = cb + ni * 16;
      float bv = bias[col];
#pragma unroll
      for (int q = 0; q < 4; ++q) {
        int rr = rb + mi * 16 + q;
        C[(long)rr * N + col] = acc[mi][ni][q] + bv;
      }
    }
}

// ---------------- hidden-split GRU: 8 blocks x 768 thr (12 waves) ----------------
// Block g owns hidden units [64g, 64g+64). Wave w: gate=w>>2, n-block=w&3.
// Cross-block h exchange via sc0sc1 (device-coherent) loads/stores; flag barrier
// with plain coherent polls — zero cache-maintenance instructions.
extern "C" __global__ void __launch_bounds__(768, 1)
k_gru4(const float* __restrict__ gi, const u16* __restrict__ Whh,
       const float* __restrict__ bhh, const float* __restrict__ eh,
       u16* __restrict__ Hb, u16* __restrict__ HS, float* __restrict__ outH,
       unsigned* __restrict__ flags) {
  __shared__ u16 Ah[32 * 512];        // swizzled h tile (32 KB)
  __shared__ float gh[3][32][65];     // gate exchange (padded)
  __shared__ u16 hbt[32][64];         // new h slice bf16
  int g = blockIdx.x, tid = threadIdx.x, wave = tid >> 6, lane = tid & 63;
  int j0 = g * 64;
  int gate = wave >> 2, nb = wave & 3;
  // B-frags (this wave's 16 output columns, all K=512) in VGPRs
  bf16x8 barr[16];
  {
    const u16* wrow = Whh + (long)(gate * 512 + j0 + nb * 16 + (lane & 15)) * 512 + ((lane >> 4) << 3);
#pragma unroll
    for (int kk = 0; kk < 16; ++kk)
      barr[kk] = *reinterpret_cast<const bf16x8*>(wrow + kk * 32);
  }
  // per-thread slots over 2048 outputs: o = s*768+tid -> (b=o>>6, u=o&63)
  float hprev[3] = {0.f, 0.f, 0.f}, bb0[3] = {}, bb1[3] = {}, bb2[3] = {};
#pragma unroll
  for (int s = 0; s < 3; ++s) {
    int o = s * 768 + tid;
    if (o < 2048) {
      int b = o >> 6, u = o & 63, j = j0 + u;
      hprev[s] = eh[b * 512 + j];
      bb0[s] = bhh[j]; bb1[s] = bhh[512 + j]; bb2[s] = bhh[1024 + j];
    }
  }
  for (int t = 0; t < 64; ++t) {
    int cur = t & 1, nxt = cur ^ 1;
    // gi prefetch (independent of h) before the poll
    float gr[3] = {}, gz[3] = {}, gn[3] = {};
#pragma unroll
    for (int s = 0; s < 3; ++s) {
      int o = s * 768 + tid;
      if (o < 2048) {
        int b = o >> 6, u = o & 63, j = j0 + u;
        const float* gp = gi + ((long)t * 32 + b) * 1536;
        gr[s] = gp[j]; gz[s] = gp[512 + j]; gn[s] = gp[1024 + j];
      }
    }
    if (t) {
      if (wave == 0) {
        const unsigned* fp = flags + (lane & 7) * 16;
        unsigned v;
        do {
          asm volatile("global_load_dword %0, %1, off sc0 sc1\n\t"
                       "s_waitcnt vmcnt(0)"
                       : "=v"(v) : "v"(fp) : "memory");
        } while (!__all((int)(v >= (unsigned)t)));
      }
      __syncthreads();
    }
    // coherent h load -> swizzled LDS tile. chunk n = l*512+tid: row=n>>6, i=n&63
    if (tid < 512) {
      const char* hsrc = (const char*)(Hb + cur * 16384);
      f32x4 d0, d1, d2, d3;
      const void* p0 = hsrc + (0 * 512 + tid) * 16;
      const void* p1 = hsrc + (1 * 512 + tid) * 16;
      const void* p2 = hsrc + (2 * 512 + tid) * 16;
      const void* p3 = hsrc + (3 * 512 + tid) * 16;
      asm volatile(
          "global_load_dwordx4 %0, %4, off sc0 sc1\n\t"
          "global_load_dwordx4 %1, %5, off sc0 sc1\n\t"
          "global_load_dwordx4 %2, %6, off sc0 sc1\n\t"
          "global_load_dwordx4 %3, %7, off sc0 sc1\n\t"
          "s_waitcnt vmcnt(0)"
          : "=v"(d0), "=v"(d1), "=v"(d2), "=v"(d3)
          : "v"(p0), "v"(p1), "v"(p2), "v"(p3)
          : "memory");
#pragma unroll
      for (int l = 0; l < 4; ++l) {
        int n = l * 512 + tid;
        int row = n >> 6, i = n & 63;
        f32x4 d = (l == 0) ? d0 : (l == 1) ? d1 : (l == 2) ? d2 : d3;
        *reinterpret_cast<f32x4*>((char*)Ah + row * 1024 + ((i * 16) ^ ((row & 7) << 4))) = d;
      }
    }
    __syncthreads();
    // MFMA: C[32 b x 16 cols] for this wave's gate/n-block
    f32x4 acc0 = {}, acc1 = {};
    int r0 = lane & 15, r1 = 16 + r0;
    int cb = (lane >> 4) << 4;
#pragma unroll
    for (int kk = 0; kk < 16; ++kk) {
      bf16x8 a0 = *reinterpret_cast<const bf16x8*>(
          (const char*)Ah + r0 * 1024 + ((kk * 64 + cb) ^ ((r0 & 7) << 4)));
      bf16x8 a1 = *reinterpret_cast<const bf16x8*>(
          (const char*)Ah + r1 * 1024 + ((kk * 64 + cb) ^ ((r1 & 7) << 4)));
      acc0 = __builtin_amdgcn_mfma_f32_16x16x32_bf16(a0, barr[kk], acc0, 0, 0, 0);
      acc1 = __builtin_amdgcn_mfma_f32_16x16x32_bf16(a1, barr[kk], acc1, 0, 0, 0);
    }
    int uc = nb * 16 + r0;
#pragma unroll
    for (int q = 0; q < 4; ++q) {
      int br = ((lane >> 4) << 2) + q;
      gh[gate][br][uc] = acc0[q];
      gh[gate][16 + br][uc] = acc1[q];
    }
    __syncthreads();
    // elementwise gate math + state update
#pragma unroll
    for (int s = 0; s < 3; ++s) {
      int o = s * 768 + tid;
      if (o < 2048) {
        int b = o >> 6, u = o & 63;
        float hr = gh[0][b][u] + bb0[s];
        float hz = gh[1][b][u] + bb1[s];
        float hn = gh[2][b][u] + bb2[s];
        float r = 1.f / (1.f + __expf(-(gr[s] + hr)));
        float z = 1.f / (1.f + __expf(-(gz[s] + hz)));
        float x = gn[s] + r * hn;
        float ax = fabsf(x), ee = __expf(-2.f * ax);
        float th = (1.f - ee) / (1.f + ee);
        th = x < 0.f ? -th : th;
        float hnew = (1.f - z) * th + z * hprev[s];
        hprev[s] = hnew;
        hbt[b][u] = f2bf(hnew);
        if (t == 63) outH[b * 512 + j0 + u] = hnew;
      }
    }
    __syncthreads();
    // wide stores: Hb (coherent) + HS (regular), then drain
    if (tid < 256) {
      int b = tid >> 3, i8 = (tid & 7) << 3;
      f32x4 dq = *reinterpret_cast<const f32x4*>(&hbt[b][i8]);
      u16* dst = Hb + nxt * 16384 + b * 512 + j0 + i8;
      asm volatile("global_store_dwordx4 %0, %1, off sc0 sc1"
                   :: "v"(dst), "v"(dq) : "memory");
      *reinterpret_cast<f32x4*>(HS + ((long)b * 64 + t) * 512 + j0 + i8) = dq;
      asm volatile("s_waitcnt vmcnt(0)" ::: "memory");
    }
    __syncthreads();
    if (tid == 0) {
      unsigned ph = (unsigned)(t + 1);
      unsigned* fdst = flags + g * 16;
      asm volatile("global_store_dword %0, %1, off sc0 sc1\n\t"
                   "s_waitcnt vmcnt(0)"
                   :: "v"(fdst), "v"(ph) : "memory");
    }
  }
}

// ---------------- in-place log_softmax over rows of 32000 ----------------
extern "C" __global__ void __launch_bounds__(512)
k_lsm(float* __restrict__ P) {
  extern __shared__ float sr[];
  __shared__ float red[8];
  long base = (long)blockIdx.x * 32000;
  int tid = threadIdx.x, wave = tid >> 6, lane = tid & 63;
  float mx = -INFINITY;
  for (int i = tid; i < 8000; i += 512) {
    float4 v = reinterpret_cast<const float4*>(P + base)[i];
    reinterpret_cast<float4*>(sr)[i] = v;
    mx = fmaxf(mx, fmaxf(fmaxf(v.x, v.y), fmaxf(v.z, v.w)));
  }
#pragma unroll
  for (int off = 32; off; off >>= 1) mx = fmaxf(mx, __shfl_down(mx, off, 64));
  if (lane == 0) red[wave] = mx;
  __syncthreads();
  if (tid == 0) {
    float m = red[0];
#pragma unroll
    for (int w = 1; w < 8; ++w) m = fmaxf(m, red[w]);
    red[0] = m;
  }
  __syncthreads();
  mx = red[0];
  __syncthreads();
  float sm = 0.f;
  for (int i = tid; i < 8000; i += 512) {
    float4 v = reinterpret_cast<const float4*>(sr)[i];
    sm += __expf(v.x - mx) + __expf(v.y - mx) + __expf(v.z - mx) + __expf(v.w - mx);
  }
#pragma unroll
  for (int off = 32; off; off >>= 1) sm += __shfl_down(sm, off, 64);
  if (lane == 0) red[wave] = sm;
  __syncthreads();
  if (tid == 0) {
    float s = 0.f;
#pragma unroll
    for (int w = 0; w < 8; ++w) s += red[w];
    red[0] = mx + __logf(s);
  }
  __syncthreads();
  float L = red[0];
  for (int i = tid; i < 8000; i += 512) {
    float4 v = reinterpret_cast<const float4*>(sr)[i];
    v.x -= L; v.y -= L; v.z -= L; v.w -= L;
    reinterpret_cast<float4*>(P + base)[i] = v;
  }
}

extern "C" void kernel_launch(void* const* d_in, const int* in_sizes, int n_in,
                              void* d_out, int out_size, void* d_ws, size_t ws_size,
                              hipStream_t stream) {
  (void)in_sizes; (void)n_in; (void)out_size;
  const float* enc_hid = (const float*)d_in[1];
  const int*   tgt     = (const int*)d_in[2];
  const float* emb     = (const float*)d_in[3];
  const float* W_ih    = (const float*)d_in[4];
  const float* W_hh    = (const float*)d_in[5];
  const float* b_ih    = (const float*)d_in[6];
  const float* b_hh    = (const float*)d_in[7];
  const float* W_out   = (const float*)d_in[8];
  const float* b_out   = (const float*)d_in[9];
  float* out = (float*)d_out;
  char* ws = (char*)d_ws;
  if (ws_size < (size_t)WS_NEED) return;

  u16* X        = (u16*)(ws + OFF_X);
  u16* Wih      = (u16*)(ws + OFF_WIH);
  u16* Whh      = (u16*)(ws + OFF_WHH);
  u16* Wout     = (u16*)(ws + OFF_WOUT);
  float* gi     = (float*)(ws + OFF_GI);
  u16* HS       = (u16*)(ws + OFF_HS);
  u16* Hb       = (u16*)(ws + OFF_HB);
  unsigned* flg = (unsigned*)(ws + OFF_FLG);

  hipFuncSetAttribute(reinterpret_cast<const void*>(k_lsm),
                      hipFuncAttributeMaxDynamicSharedMemorySize, 131072);

  k_cast<<<96, 256, 0, stream>>>(W_ih, Wih, 1536 * 256 / 4);
  k_cast<<<192, 256, 0, stream>>>(W_hh, Whh, 1536 * 512 / 4);
  k_cast<<<2048, 256, 0, stream>>>(W_out, Wout, 32000 * 512 / 4);
  k_embed<<<256, 256, 0, stream>>>(emb, tgt, X);
  k_init<<<64, 256, 0, stream>>>(enc_hid, Hb, flg);
  k_gemm_bt<<<(1536 / 128) * (2048 / 128), 256, 0, stream>>>(X, Wih, b_ih, gi, 2048, 1536, 256);
  k_gru4<<<8, 768, 0, stream>>>(gi, Whh, b_hh, enc_hid, Hb, HS, out + BTV, flg);
  k_gemm_bt<<<(32000 / 128) * (2048 / 128), 256, 0, stream>>>(HS, Wout, b_out, out, 2048, 32000, 512);
  k_lsm<<<2048, 512, 128000, stream>>>(out);
}

// Round 5
// 464.772 us; speedup vs baseline: 2.2698x; 1.2684x over previous
//
#include <hip/hip_runtime.h>
#include <hip/hip_bf16.h>
#include <math.h>

// GRU decoder: embed+relu -> gi GEMM -> same-XCD hidden-split GRU (leader-elected,
// L2-coherent data + LLC flags) -> vocab projection (bf16 MFMA, optional bf16-logit
// fusion) -> log_softmax.

typedef __bf16 bf16x8 __attribute__((ext_vector_type(8)));
typedef float  f32x4  __attribute__((ext_vector_type(4)));
typedef unsigned short u16;
typedef u16 u16x8v __attribute__((ext_vector_type(8)));
typedef u16 u16x4v __attribute__((ext_vector_type(4)));

#define BTV (32L * 64 * 32000)

// ---- ws layout (bytes) ----
#define OFF_X    (0L)
#define SZ_X     (2048L * 256 * 2)
#define OFF_WIH  (OFF_X + SZ_X)
#define SZ_WIH   (1536L * 256 * 2)
#define OFF_WHH  (OFF_WIH + SZ_WIH)
#define SZ_WHH   (1536L * 512 * 2)
#define OFF_WOUT (OFF_WHH + SZ_WHH)
#define SZ_WOUT  (32000L * 512 * 2)
#define OFF_GI   (OFF_WOUT + SZ_WOUT)
#define SZ_GI    (2048L * 1536 * 4)
#define OFF_HS   (OFF_GI + SZ_GI)
#define SZ_HS    (2048L * 512 * 2)
#define OFF_HB   (OFF_HS + SZ_HS)
#define SZ_HB    (2L * 32 * 512 * 2)
#define OFF_FLG  (OFF_HB + SZ_HB)
#define SZ_FLG   (512L)
#define OFF_EV   (OFF_FLG + SZ_FLG)
#define SZ_EV    (64L)
#define WS_NEED  (OFF_EV + SZ_EV)
#define OFF_LG   (WS_NEED + 4096 - (WS_NEED % 4096))
#define SZ_LG    (2048L * 32000 * 2)
#define WS_BIG   (OFF_LG + SZ_LG)

__device__ __forceinline__ u16 f2bf(float f) {
  union { float f; unsigned u; } a; a.f = f;
  unsigned r = a.u + 0x7fffu + ((a.u >> 16) & 1u);
  return (u16)(r >> 16);
}

__device__ __forceinline__ float bf2f(u16 u) {
  union { unsigned u; float f; } a; a.u = ((unsigned)u) << 16;
  return a.f;
}

__device__ __forceinline__ void gload16(const void* g, void* l) {
  __builtin_amdgcn_global_load_lds(
      (const __attribute__((address_space(1))) unsigned int*)g,
      (__attribute__((address_space(3))) unsigned int*)l, 16, 0, 0);
}

// ---------------- cast f32 -> bf16 (grid-stride float4) ----------------
extern "C" __global__ void k_cast(const float* __restrict__ s, u16* __restrict__ d, int n4) {
  int i = blockIdx.x * blockDim.x + threadIdx.x;
  int st = gridDim.x * blockDim.x;
  for (; i < n4; i += st) {
    float4 v = reinterpret_cast<const float4*>(s)[i];
    u16x4v o; o.x = f2bf(v.x); o.y = f2bf(v.y); o.z = f2bf(v.z); o.w = f2bf(v.w);
    reinterpret_cast<u16x4v*>(d)[i] = o;
  }
}

// ---------------- embed + relu -> X[t*32+b][256] bf16 ----------------
extern "C" __global__ void k_embed(const float* __restrict__ emb, const int* __restrict__ tgt,
                                   u16* __restrict__ X) {
  int idx = blockIdx.x * 256 + threadIdx.x;  // 65536 total
  int row = idx >> 5;                        // 0..2047  (= t*32 + b)
  int c8  = (idx & 31) << 3;
  int t = row >> 5, b = row & 31;
  int token = (t == 0) ? 0 : tgt[b * 64 + t - 1];
  const float* e = emb + (long)token * 256 + c8;
  u16x8v o;
#pragma unroll
  for (int i = 0; i < 8; ++i) { float v = e[i]; o[i] = f2bf(v > 0.f ? v : 0.f); }
  *reinterpret_cast<u16x8v*>(X + (long)row * 256 + c8) = o;
}

// ---------------- flags (LLC) + election vars init ----------------
extern "C" __global__ void k_init(unsigned* flags, unsigned* evars) {
  int i = threadIdx.x;
  if (i < 128) {
    unsigned z = 0u;
    asm volatile("global_store_dword %0, %1, off sc0 sc1"
                 :: "v"(flags + i), "v"(z) : "memory");
  }
  if (i < 10) atomicExch(&evars[i], i == 8 ? 0xFFFFFFFFu : 0u);
}

// ---------------- generic bf16 MFMA GEMM, C = A*B^T + bias ----------------
template <bool BF16OUT>
__global__ void __launch_bounds__(256)
k_gemm_t(const u16* __restrict__ A, const u16* __restrict__ B,
         const float* __restrict__ bias, float* __restrict__ C,
         u16* __restrict__ C2, int M, int N, int K) {
  __shared__ u16 At[128 * 32];
  __shared__ u16 Bt[128 * 32];
  int mt = M >> 7;
  int bn = blockIdx.x / mt, bm = blockIdx.x % mt;
  int tid = threadIdx.x, wave = tid >> 6, lane = tid & 63;
  int wr = wave >> 1, wc = wave & 1;
  f32x4 acc[4][4] = {};
  const u16* ga = A + (long)(bm * 128 + wave * 32 + (lane >> 2)) * K + ((lane & 3) << 3);
  const u16* gb = B + (long)(bn * 128 + wave * 32 + (lane >> 2)) * K + ((lane & 3) << 3);
  u16* la0 = &At[wave * 1024]; u16* la1 = la0 + 512;
  u16* lb0 = &Bt[wave * 1024]; u16* lb1 = lb0 + 512;
  long k16 = 16L * K;
  for (int k0 = 0; k0 < K; k0 += 32) {
    if (k0) __syncthreads();
    gload16(ga + k0, la0);
    gload16(ga + k16 + k0, la1);
    gload16(gb + k0, lb0);
    gload16(gb + k16 + k0, lb1);
    __syncthreads();
    bf16x8 af[4], bfr[4];
#pragma unroll
    for (int mi = 0; mi < 4; ++mi)
      af[mi] = *reinterpret_cast<const bf16x8*>(
          &At[(wr * 64 + mi * 16 + (lane & 15)) * 32 + ((lane >> 4) << 3)]);
#pragma unroll
    for (int ni = 0; ni < 4; ++ni)
      bfr[ni] = *reinterpret_cast<const bf16x8*>(
          &Bt[(wc * 64 + ni * 16 + (lane & 15)) * 32 + ((lane >> 4) << 3)]);
#pragma unroll
    for (int mi = 0; mi < 4; ++mi)
#pragma unroll
      for (int ni = 0; ni < 4; ++ni)
        acc[mi][ni] = __builtin_amdgcn_mfma_f32_16x16x32_bf16(af[mi], bfr[ni], acc[mi][ni], 0, 0, 0);
  }
  int rb = bm * 128 + wr * 64 + ((lane >> 4) << 2);
  int cb = bn * 128 + wc * 64 + (lane & 15);
#pragma unroll
  for (int mi = 0; mi < 4; ++mi)
#pragma unroll
    for (int ni = 0; ni < 4; ++ni) {
      int col = cb + ni * 16;
      float bv = bias[col];
#pragma unroll
      for (int q = 0; q < 4; ++q) {
        int rr = rb + mi * 16 + q;
        if (BF16OUT) C2[(long)rr * N + col] = f2bf(acc[mi][ni][q] + bv);
        else         C[(long)rr * N + col] = acc[mi][ni][q] + bv;
      }
    }
}

// ---------------- same-XCD hidden-split GRU: 64 blocks launched, 8 workers ----------------
// Leader election picks one XCD (>=8 resident blocks by pigeonhole); its first 8
// claimants become workers (slice j0 = role*64). h data: sc0 (XCD-L2 coherent);
// step flags: sc0 sc1 (LLC). 12 waves = 3 gates x 2 u-halves x 2 K-slices.
extern "C" __global__ void __launch_bounds__(768, 1)
k_gru5(const float* __restrict__ gi, const u16* __restrict__ Whh,
       const float* __restrict__ bhh, const float* __restrict__ eh,
       u16* __restrict__ Hb, u16* __restrict__ HS, float* __restrict__ outH,
       unsigned* flags, unsigned* evars) {
  __shared__ u16 Ah[32 * 512];        // swizzled h tile (32 KB)
  __shared__ float gh[3][32][65];
  __shared__ int role_s;
  int tid = threadIdx.x, wave = tid >> 6, lane = tid & 63;
  if (tid == 0) {
    unsigned xcc;
    asm volatile("s_getreg_b32 %0, hwreg(20, 0, 32)" : "=s"(xcc));
    xcc &= 7u;
    unsigned arr = atomicAdd(&evars[xcc], 1u);
    if (arr == 7u) atomicCAS(&evars[8], 0xFFFFFFFFu, xcc);
    unsigned L = 0xFFFFFFFFu;
    for (int it = 0; it < (1 << 24) && L == 0xFFFFFFFFu; ++it) {
      asm volatile("global_load_dword %0, %1, off sc0 sc1\n\ts_waitcnt vmcnt(0)"
                   : "=v"(L) : "v"(evars + 8) : "memory");
    }
    int role = -1;
    if (L == xcc) {
      unsigned c = atomicAdd(&evars[9], 1u);
      if (c < 8u) role = (int)c;
    }
    role_s = role;
  }
  __syncthreads();
  int g = role_s;
  if (g < 0) return;
  int j0 = g * 64;
  int gate = wave >> 2;            // 0..2
  int uh = (wave >> 1) & 1;        // u half
  int sig = wave & 1;              // K slice
  // B-frags: W[gate*512 + j0 + uh*32 + ut*16 + r, sig*256 + kt*32 + c], 16 frags in VGPRs
  bf16x8 barr[2][8];
  {
    const u16* wbase = Whh + (long)(gate * 512 + j0 + uh * 32) * 512 + sig * 256;
#pragma unroll
    for (int ut = 0; ut < 2; ++ut)
#pragma unroll
      for (int kt = 0; kt < 8; ++kt)
        barr[ut][kt] = *reinterpret_cast<const bf16x8*>(
            wbase + (long)(ut * 16 + (lane & 15)) * 512 + kt * 32 + ((lane >> 4) << 3));
  }
  // per-thread output slots: o = s*768+tid over 2048 outputs (b=o>>6, u=o&63)
  float hprev[3] = {0.f, 0.f, 0.f}, bb0[3] = {}, bb1[3] = {}, bb2[3] = {};
#pragma unroll
  for (int s = 0; s < 3; ++s) {
    int o = s * 768 + tid;
    if (o < 2048) {
      int b = o >> 6, u = o & 63, j = j0 + u;
      hprev[s] = eh[b * 512 + j];
      bb0[s] = bhh[j]; bb1[s] = bhh[512 + j]; bb2[s] = bhh[1024 + j];
    }
  }
  for (int t = 0; t < 64; ++t) {
    int cur = t & 1, nxt = cur ^ 1;
    // gi prefetch (independent of h) before the poll
    float grv[3] = {}, gzv[3] = {}, gnv[3] = {};
#pragma unroll
    for (int s = 0; s < 3; ++s) {
      int o = s * 768 + tid;
      if (o < 2048) {
        int b = o >> 6, u = o & 63, j = j0 + u;
        const float* gp = gi + ((long)t * 32 + b) * 1536;
        grv[s] = gp[j]; gzv[s] = gp[512 + j]; gnv[s] = gp[1024 + j];
      }
    }
    if (t) {
      if (wave == 0) {
        const unsigned* fp = flags + (lane & 7) * 16;
        unsigned v;
        do {
          asm volatile("global_load_dword %0, %1, off sc0 sc1\n\ts_waitcnt vmcnt(0)"
                       : "=v"(v) : "v"(fp) : "memory");
        } while (!__all((int)(v >= (unsigned)t)));
      }
      __syncthreads();
      // h load (XCD-L2 coherent) -> swizzled LDS
      if (tid < 512) {
        const char* hsrc = (const char*)(Hb + cur * 16384);
        f32x4 d0, d1, d2, d3;
        const void* p0 = hsrc + (0 * 512 + tid) * 16;
        const void* p1 = hsrc + (1 * 512 + tid) * 16;
        const void* p2 = hsrc + (2 * 512 + tid) * 16;
        const void* p3 = hsrc + (3 * 512 + tid) * 16;
        asm volatile(
            "global_load_dwordx4 %0, %4, off sc0\n\t"
            "global_load_dwordx4 %1, %5, off sc0\n\t"
            "global_load_dwordx4 %2, %6, off sc0\n\t"
            "global_load_dwordx4 %3, %7, off sc0\n\t"
            "s_waitcnt vmcnt(0)"
            : "=v"(d0), "=v"(d1), "=v"(d2), "=v"(d3)
            : "v"(p0), "v"(p1), "v"(p2), "v"(p3)
            : "memory");
#pragma unroll
        for (int l = 0; l < 4; ++l) {
          int n = l * 512 + tid;
          int row = n >> 6, i = n & 63;
          f32x4 d = (l == 0) ? d0 : (l == 1) ? d1 : (l == 2) ? d2 : d3;
          *reinterpret_cast<f32x4*>((char*)Ah + row * 1024 + ((i * 16) ^ ((row & 7) << 4))) = d;
        }
      }
    } else {
      // t=0: stage h0 from eh (clean input), f32 -> bf16
      if (tid < 512) {
#pragma unroll
        for (int l = 0; l < 4; ++l) {
          int n = l * 512 + tid;
          int row = n >> 6, i = n & 63;
          const float* p = eh + row * 512 + i * 8;
          float4 aa = *reinterpret_cast<const float4*>(p);
          float4 bb = *reinterpret_cast<const float4*>(p + 4);
          u16x8v o8;
          o8[0] = f2bf(aa.x); o8[1] = f2bf(aa.y); o8[2] = f2bf(aa.z); o8[3] = f2bf(aa.w);
          o8[4] = f2bf(bb.x); o8[5] = f2bf(bb.y); o8[6] = f2bf(bb.z); o8[7] = f2bf(bb.w);
          *reinterpret_cast<u16x8v*>((char*)Ah + row * 1024 + ((i * 16) ^ ((row & 7) << 4))) = o8;
        }
      }
    }
    __syncthreads();
    // MFMA partials: [32b x 32u x 256k] per wave
    f32x4 acc[2][2] = {};
    int r15 = lane & 15;
    int cbyte = sig * 512 + ((lane >> 4) << 4);
#pragma unroll
    for (int kt = 0; kt < 8; ++kt) {
      bf16x8 a0 = *reinterpret_cast<const bf16x8*>(
          (const char*)Ah + r15 * 1024 + ((kt * 64 + cbyte) ^ ((r15 & 7) << 4)));
      bf16x8 a1 = *reinterpret_cast<const bf16x8*>(
          (const char*)Ah + (16 + r15) * 1024 + ((kt * 64 + cbyte) ^ ((r15 & 7) << 4)));
#pragma unroll
      for (int ut = 0; ut < 2; ++ut) {
        acc[0][ut] = __builtin_amdgcn_mfma_f32_16x16x32_bf16(a0, barr[ut][kt], acc[0][ut], 0, 0, 0);
        acc[1][ut] = __builtin_amdgcn_mfma_f32_16x16x32_bf16(a1, barr[ut][kt], acc[1][ut], 0, 0, 0);
      }
    }
    // K-slice reduction into gh: sig0 writes, sync, sig1 adds
    int ucol = uh * 32 + r15;
    int brow = (lane >> 4) << 2;
    if (sig == 0) {
#pragma unroll
      for (int q = 0; q < 4; ++q) {
        gh[gate][brow + q][ucol]           = acc[0][0][q];
        gh[gate][brow + q][ucol + 16]      = acc[0][1][q];
        gh[gate][16 + brow + q][ucol]      = acc[1][0][q];
        gh[gate][16 + brow + q][ucol + 16] = acc[1][1][q];
      }
    }
    __syncthreads();
    if (sig == 1) {
#pragma unroll
      for (int q = 0; q < 4; ++q) {
        gh[gate][brow + q][ucol]           += acc[0][0][q];
        gh[gate][brow + q][ucol + 16]      += acc[0][1][q];
        gh[gate][16 + brow + q][ucol]      += acc[1][0][q];
        gh[gate][16 + brow + q][ucol + 16] += acc[1][1][q];
      }
    }
    __syncthreads();
    // elementwise gate math + direct coherent stores
#pragma unroll
    for (int s = 0; s < 3; ++s) {
      int o = s * 768 + tid;
      if (o < 2048) {
        int b = o >> 6, u = o & 63, j = j0 + u;
        float hr = gh[0][b][u] + bb0[s];
        float hz = gh[1][b][u] + bb1[s];
        float hn = gh[2][b][u] + bb2[s];
        float r = 1.f / (1.f + __expf(-(grv[s] + hr)));
        float z = 1.f / (1.f + __expf(-(gzv[s] + hz)));
        float x = gnv[s] + r * hn;
        float ax = fabsf(x), ee = __expf(-2.f * ax);
        float th = (1.f - ee) / (1.f + ee);
        th = x < 0.f ? -th : th;
        float hnew = (1.f - z) * th + z * hprev[s];
        hprev[s] = hnew;
        u16 hb = f2bf(hnew);
        u16* hdst = Hb + nxt * 16384 + b * 512 + j;
        asm volatile("global_store_short %0, %1, off sc0"
                     :: "v"(hdst), "v"((unsigned)hb) : "memory");
        HS[((long)b * 64 + t) * 512 + j] = hb;
        if (t == 63) outH[b * 512 + j] = hnew;
      }
    }
    asm volatile("s_waitcnt vmcnt(0)" ::: "memory");
    __syncthreads();
    if (tid == 0) {
      unsigned ph = (unsigned)(t + 1);
      asm volatile("global_store_dword %0, %1, off sc0 sc1\n\ts_waitcnt vmcnt(0)"
                   :: "v"(flags + g * 16), "v"(ph) : "memory");
    }
  }
}

// ---------------- log_softmax, f32 in-place ----------------
extern "C" __global__ void __launch_bounds__(512)
k_lsm(float* __restrict__ P) {
  extern __shared__ float sr[];
  __shared__ float red[8];
  long base = (long)blockIdx.x * 32000;
  int tid = threadIdx.x, wave = tid >> 6, lane = tid & 63;
  float mx = -INFINITY;
  for (int i = tid; i < 8000; i += 512) {
    float4 v = reinterpret_cast<const float4*>(P + base)[i];
    reinterpret_cast<float4*>(sr)[i] = v;
    mx = fmaxf(mx, fmaxf(fmaxf(v.x, v.y), fmaxf(v.z, v.w)));
  }
#pragma unroll
  for (int off = 32; off; off >>= 1) mx = fmaxf(mx, __shfl_down(mx, off, 64));
  if (lane == 0) red[wave] = mx;
  __syncthreads();
  if (tid == 0) {
    float m = red[0];
#pragma unroll
    for (int w = 1; w < 8; ++w) m = fmaxf(m, red[w]);
    red[0] = m;
  }
  __syncthreads();
  mx = red[0];
  __syncthreads();
  float sm = 0.f;
  for (int i = tid; i < 8000; i += 512) {
    float4 v = reinterpret_cast<const float4*>(sr)[i];
    sm += __expf(v.x - mx) + __expf(v.y - mx) + __expf(v.z - mx) + __expf(v.w - mx);
  }
#pragma unroll
  for (int off = 32; off; off >>= 1) sm += __shfl_down(sm, off, 64);
  if (lane == 0) red[wave] = sm;
  __syncthreads();
  if (tid == 0) {
    float s = 0.f;
#pragma unroll
    for (int w = 0; w < 8; ++w) s += red[w];
    red[0] = mx + __logf(s);
  }
  __syncthreads();
  float L = red[0];
  for (int i = tid; i < 8000; i += 512) {
    float4 v = reinterpret_cast<const float4*>(sr)[i];
    v.x -= L; v.y -= L; v.z -= L; v.w -= L;
    reinterpret_cast<float4*>(P + base)[i] = v;
  }
}

// ---------------- log_softmax, bf16 logits -> f32 out ----------------
extern "C" __global__ void __launch_bounds__(512)
k_lsm_b(const u16* __restrict__ LG, float* __restrict__ P) {
  extern __shared__ u16 srb[];
  __shared__ float red[8];
  long base = (long)blockIdx.x * 32000;
  int tid = threadIdx.x, wave = tid >> 6, lane = tid & 63;
  float mx = -INFINITY;
  for (int i = tid; i < 4000; i += 512) {
    u16x8v v = reinterpret_cast<const u16x8v*>(LG + base)[i];
    reinterpret_cast<u16x8v*>(srb)[i] = v;
#pragma unroll
    for (int e = 0; e < 8; ++e) mx = fmaxf(mx, bf2f(v[e]));
  }
#pragma unroll
  for (int off = 32; off; off >>= 1) mx = fmaxf(mx, __shfl_down(mx, off, 64));
  if (lane == 0) red[wave] = mx;
  __syncthreads();
  if (tid == 0) {
    float m = red[0];
#pragma unroll
    for (int w = 1; w < 8; ++w) m = fmaxf(m, red[w]);
    red[0] = m;
  }
  __syncthreads();
  mx = red[0];
  __syncthreads();
  float sm = 0.f;
  for (int i = tid; i < 4000; i += 512) {
    u16x8v v = reinterpret_cast<const u16x8v*>(srb)[i];
#pragma unroll
    for (int e = 0; e < 8; ++e) sm += __expf(bf2f(v[e]) - mx);
  }
#pragma unroll
  for (int off = 32; off; off >>= 1) sm += __shfl_down(sm, off, 64);
  if (lane == 0) red[wave] = sm;
  __syncthreads();
  if (tid == 0) {
    float s = 0.f;
#pragma unroll
    for (int w = 0; w < 8; ++w) s += red[w];
    red[0] = mx + __logf(s);
  }
  __syncthreads();
  float L = red[0];
  for (int i = tid; i < 4000; i += 512) {
    u16x8v v = reinterpret_cast<const u16x8v*>(srb)[i];
    float4 o1, o2;
    o1.x = bf2f(v[0]) - L; o1.y = bf2f(v[1]) - L; o1.z = bf2f(v[2]) - L; o1.w = bf2f(v[3]) - L;
    o2.x = bf2f(v[4]) - L; o2.y = bf2f(v[5]) - L; o2.z = bf2f(v[6]) - L; o2.w = bf2f(v[7]) - L;
    reinterpret_cast<float4*>(P + base + (long)i * 8)[0] = o1;
    reinterpret_cast<float4*>(P + base + (long)i * 8)[1] = o2;
  }
}

extern "C" void kernel_launch(void* const* d_in, const int* in_sizes, int n_in,
                              void* d_out, int out_size, void* d_ws, size_t ws_size,
                              hipStream_t stream) {
  (void)in_sizes; (void)n_in; (void)out_size;
  const float* enc_hid = (const float*)d_in[1];
  const int*   tgt     = (const int*)d_in[2];
  const float* emb     = (const float*)d_in[3];
  const float* W_ih    = (const float*)d_in[4];
  const float* W_hh    = (const float*)d_in[5];
  const float* b_ih    = (const float*)d_in[6];
  const float* b_hh    = (const float*)d_in[7];
  const float* W_out   = (const float*)d_in[8];
  const float* b_out   = (const float*)d_in[9];
  float* out = (float*)d_out;
  char* ws = (char*)d_ws;
  if (ws_size < (size_t)WS_NEED) return;
  bool big = ws_size >= (size_t)WS_BIG;

  u16* X        = (u16*)(ws + OFF_X);
  u16* Wih      = (u16*)(ws + OFF_WIH);
  u16* Whh      = (u16*)(ws + OFF_WHH);
  u16* Wout     = (u16*)(ws + OFF_WOUT);
  float* gi     = (float*)(ws + OFF_GI);
  u16* HS       = (u16*)(ws + OFF_HS);
  u16* Hb       = (u16*)(ws + OFF_HB);
  unsigned* flg = (unsigned*)(ws + OFF_FLG);
  unsigned* ev  = (unsigned*)(ws + OFF_EV);
  u16* LG       = (u16*)(ws + OFF_LG);

  hipFuncSetAttribute(reinterpret_cast<const void*>(k_lsm),
                      hipFuncAttributeMaxDynamicSharedMemorySize, 131072);
  hipFuncSetAttribute(reinterpret_cast<const void*>(k_lsm_b),
                      hipFuncAttributeMaxDynamicSharedMemorySize, 65536);

  k_cast<<<96, 256, 0, stream>>>(W_ih, Wih, 1536 * 256 / 4);
  k_cast<<<192, 256, 0, stream>>>(W_hh, Whh, 1536 * 512 / 4);
  k_cast<<<2048, 256, 0, stream>>>(W_out, Wout, 32000 * 512 / 4);
  k_embed<<<256, 256, 0, stream>>>(emb, tgt, X);
  k_init<<<1, 256, 0, stream>>>(flg, ev);
  k_gemm_t<false><<<(1536 / 128) * (2048 / 128), 256, 0, stream>>>(
      X, Wih, b_ih, gi, nullptr, 2048, 1536, 256);
  k_gru5<<<64, 768, 0, stream>>>(gi, Whh, b_hh, enc_hid, Hb, HS, out + BTV, flg, ev);
  if (big) {
    k_gemm_t<true><<<(32000 / 128) * (2048 / 128), 256, 0, stream>>>(
        HS, Wout, b_out, nullptr, LG, 2048, 32000, 512);
    k_lsm_b<<<2048, 512, 64000, stream>>>(LG, out);
  } else {
    k_gemm_t<false><<<(32000 / 128) * (2048 / 128), 256, 0, stream>>>(
        HS, Wout, b_out, out, nullptr, 2048, 32000, 512);
    k_lsm<<<2048, 512, 128000, stream>>>(out);
  }
}

// Round 7
// 450.256 us; speedup vs baseline: 2.3430x; 1.0322x over previous
//
#include <hip/hip_runtime.h>
#include <hip/hip_bf16.h>
#include <math.h>

// GRU decoder: embed+relu -> gi GEMM -> same-XCD hidden-split GRU (leader-elected,
// HS as the sync medium, W in VGPRs) -> vocab projection (bf16 logits aliased into
// the first half of each d_out f32 row slot) -> log_softmax (bf16 in, f32 out).

typedef __bf16 bf16x8 __attribute__((ext_vector_type(8)));
typedef float  f32x4  __attribute__((ext_vector_type(4)));
typedef unsigned short u16;
typedef u16 u16x8v __attribute__((ext_vector_type(8)));
typedef u16 u16x4v __attribute__((ext_vector_type(4)));

#define BTV (32L * 64 * 32000)
// bf16 logit row stride inside d_out: one f32 row slot = 32000*4 = 128000 bytes
// = 64000 u16. Row r's bf16 copy sits in the FIRST HALF of row r's own slot.
#define LDC2 64000L

// ---- ws layout (bytes) ----
#define OFF_X    (0L)
#define SZ_X     (2048L * 256 * 2)
#define OFF_WIH  (OFF_X + SZ_X)
#define SZ_WIH   (1536L * 256 * 2)
#define OFF_WHH  (OFF_WIH + SZ_WIH)
#define SZ_WHH   (1536L * 512 * 2)
#define OFF_WOUT (OFF_WHH + SZ_WHH)
#define SZ_WOUT  (32000L * 512 * 2)
#define OFF_GI   (OFF_WOUT + SZ_WOUT)
#define SZ_GI    (2048L * 1536 * 4)
#define OFF_HS   (OFF_GI + SZ_GI)
#define SZ_HS    (2048L * 512 * 2)
#define OFF_FLG  (OFF_HS + SZ_HS)
#define SZ_FLG   (512L)
#define OFF_EV   (OFF_FLG + SZ_FLG)
#define SZ_EV    (64L)
#define WS_NEED  (OFF_EV + SZ_EV)

__device__ __forceinline__ u16 f2bf(float f) {
  union { float f; unsigned u; } a; a.f = f;
  unsigned r = a.u + 0x7fffu + ((a.u >> 16) & 1u);
  return (u16)(r >> 16);
}

__device__ __forceinline__ float bf2f(u16 u) {
  union { unsigned u; float f; } a; a.u = ((unsigned)u) << 16;
  return a.f;
}

__device__ __forceinline__ void gload16(const void* g, void* l) {
  __builtin_amdgcn_global_load_lds(
      (const __attribute__((address_space(1))) unsigned int*)g,
      (__attribute__((address_space(3))) unsigned int*)l, 16, 0, 0);
}

// ---------------- cast f32 -> bf16 (grid-stride float4) ----------------
extern "C" __global__ void k_cast(const float* __restrict__ s, u16* __restrict__ d, int n4) {
  int i = blockIdx.x * blockDim.x + threadIdx.x;
  int st = gridDim.x * blockDim.x;
  for (; i < n4; i += st) {
    float4 v = reinterpret_cast<const float4*>(s)[i];
    u16x4v o; o.x = f2bf(v.x); o.y = f2bf(v.y); o.z = f2bf(v.z); o.w = f2bf(v.w);
    reinterpret_cast<u16x4v*>(d)[i] = o;
  }
}

// ---------------- embed + relu -> X[t*32+b][256] bf16 ----------------
extern "C" __global__ void k_embed(const float* __restrict__ emb, const int* __restrict__ tgt,
                                   u16* __restrict__ X) {
  int idx = blockIdx.x * 256 + threadIdx.x;  // 65536 total
  int row = idx >> 5;                        // 0..2047  (= t*32 + b)
  int c8  = (idx & 31) << 3;
  int t = row >> 5, b = row & 31;
  int token = (t == 0) ? 0 : tgt[b * 64 + t - 1];
  const float* e = emb + (long)token * 256 + c8;
  u16x8v o;
#pragma unroll
  for (int i = 0; i < 8; ++i) { float v = e[i]; o[i] = f2bf(v > 0.f ? v : 0.f); }
  *reinterpret_cast<u16x8v*>(X + (long)row * 256 + c8) = o;
}

// ---------------- flags (LLC) + election vars init ----------------
extern "C" __global__ void k_init(unsigned* flags, unsigned* evars) {
  int i = threadIdx.x;
  if (i < 128) {
    unsigned z = 0u;
    asm volatile("global_store_dword %0, %1, off sc0 sc1"
                 :: "v"(flags + i), "v"(z) : "memory");
  }
  if (i < 10) atomicExch(&evars[i], i == 8 ? 0xFFFFFFFFu : 0u);
}

// ---------------- generic bf16 MFMA GEMM, C = A*B^T + bias ----------------
// BF16OUT: writes u16 logits to C2 with row stride ldc2 (d_out row-slot aliasing).
template <bool BF16OUT>
__global__ void __launch_bounds__(256)
k_gemm_t(const u16* __restrict__ A, const u16* __restrict__ B,
         const float* __restrict__ bias, float* __restrict__ C,
         u16* __restrict__ C2, int M, int N, int K, long ldc2) {
  __shared__ u16 At[128 * 32];
  __shared__ u16 Bt[128 * 32];
  int mt = M >> 7;
  int bn = blockIdx.x / mt, bm = blockIdx.x % mt;
  int tid = threadIdx.x, wave = tid >> 6, lane = tid & 63;
  int wr = wave >> 1, wc = wave & 1;
  f32x4 acc[4][4] = {};
  const u16* ga = A + (long)(bm * 128 + wave * 32 + (lane >> 2)) * K + ((lane & 3) << 3);
  const u16* gb = B + (long)(bn * 128 + wave * 32 + (lane >> 2)) * K + ((lane & 3) << 3);
  u16* la0 = &At[wave * 1024]; u16* la1 = la0 + 512;
  u16* lb0 = &Bt[wave * 1024]; u16* lb1 = lb0 + 512;
  long k16 = 16L * K;
  for (int k0 = 0; k0 < K; k0 += 32) {
    if (k0) __syncthreads();
    gload16(ga + k0, la0);
    gload16(ga + k16 + k0, la1);
    gload16(gb + k0, lb0);
    gload16(gb + k16 + k0, lb1);
    __syncthreads();
    bf16x8 af[4], bfr[4];
#pragma unroll
    for (int mi = 0; mi < 4; ++mi)
      af[mi] = *reinterpret_cast<const bf16x8*>(
          &At[(wr * 64 + mi * 16 + (lane & 15)) * 32 + ((lane >> 4) << 3)]);
#pragma unroll
    for (int ni = 0; ni < 4; ++ni)
      bfr[ni] = *reinterpret_cast<const bf16x8*>(
          &Bt[(wc * 64 + ni * 16 + (lane & 15)) * 32 + ((lane >> 4) << 3)]);
#pragma unroll
    for (int mi = 0; mi < 4; ++mi)
#pragma unroll
      for (int ni = 0; ni < 4; ++ni)
        acc[mi][ni] = __builtin_amdgcn_mfma_f32_16x16x32_bf16(af[mi], bfr[ni], acc[mi][ni], 0, 0, 0);
  }
  int rb = bm * 128 + wr * 64 + ((lane >> 4) << 2);
  int cb = bn * 128 + wc * 64 + (lane & 15);
#pragma unroll
  for (int mi = 0; mi < 4; ++mi)
#pragma unroll
    for (int ni = 0; ni < 4; ++ni) {
      int col = cb + ni * 16;
      float bv = bias[col];
#pragma unroll
      for (int q = 0; q < 4; ++q) {
        int rr = rb + mi * 16 + q;
        if (BF16OUT) C2[(long)rr * ldc2 + col] = f2bf(acc[mi][ni][q] + bv);
        else         C[(long)rr * N + col] = acc[mi][ni][q] + bv;
      }
    }
}

// ---------------- same-XCD hidden-split GRU (HS is the sync medium) ----------------
// 64 blocks launched; leader election picks one XCD, first 8 claimants work
// (slice j0 = role*64). 12 waves = 3 gates x 2 u-halves x 2 K-slices. All h traffic
// via HS with sc0 (XCD-L2); step flags sc0 sc1 (LLC). All addressing hoisted.
extern "C" __global__ void __launch_bounds__(768, 1)
k_gru6(const float* __restrict__ gi, const u16* __restrict__ Whh,
       const float* __restrict__ bhh, const float* __restrict__ eh,
       u16* __restrict__ HS, float* __restrict__ outH,
       unsigned* flags, unsigned* evars) {
  __shared__ u16 Ah[32 * 512];           // swizzled h tile (32 KB)
  __shared__ float gh[3][2][32][66];     // per-K-slice gate partials
  __shared__ int role_s;
  int tid = threadIdx.x, wave = tid >> 6, lane = tid & 63;
  if (tid == 0) {
    unsigned xcc;
    asm volatile("s_getreg_b32 %0, hwreg(20, 0, 32)" : "=s"(xcc));
    xcc &= 7u;
    unsigned arr = atomicAdd(&evars[xcc], 1u);
    if (arr == 7u) atomicCAS(&evars[8], 0xFFFFFFFFu, xcc);
    unsigned L = 0xFFFFFFFFu;
    for (int it = 0; it < (1 << 24) && L == 0xFFFFFFFFu; ++it) {
      asm volatile("global_load_dword %0, %1, off sc0 sc1\n\ts_waitcnt vmcnt(0)"
                   : "=v"(L) : "v"(evars + 8) : "memory");
    }
    int role = -1;
    if (L == xcc) {
      unsigned c = atomicAdd(&evars[9], 1u);
      if (c < 8u) role = (int)c;
    }
    role_s = role;
  }
  __syncthreads();
  int g = role_s;
  if (g < 0) return;
  int j0 = g * 64;
  int gate = wave >> 2, uh = (wave >> 1) & 1, sig = wave & 1;
  // B-frags in VGPRs (this wave's 32 output cols x its K-half)
  bf16x8 barr[2][8];
  {
    const u16* wbase = Whh + (long)(gate * 512 + j0 + uh * 32) * 512 + sig * 256;
#pragma unroll
    for (int ut = 0; ut < 2; ++ut)
#pragma unroll
      for (int kt = 0; kt < 8; ++kt)
        barr[ut][kt] = *reinterpret_cast<const bf16x8*>(
            wbase + (long)(ut * 16 + (lane & 15)) * 512 + kt * 32 + ((lane >> 4) << 3));
  }
  // per-thread output slots: o = s*768+tid; s=0,1 always active, s=2 iff tid<512
  bool act2 = tid < 512;
  float hprev[3] = {}, bb0[3] = {}, bb1[3] = {}, bb2[3] = {};
  const float* gp0; const float* gp1; const float* gp2 = nullptr;
  u16* hs0; u16* hs1; u16* hs2 = nullptr;
  int b_[3], u_[3];
#pragma unroll
  for (int s = 0; s < 3; ++s) {
    int o = s * 768 + tid;
    if (o < 2048) {
      int b = o >> 6, u = o & 63, j = j0 + u;
      b_[s] = b; u_[s] = u;
      hprev[s] = eh[b * 512 + j];
      bb0[s] = bhh[j]; bb1[s] = bhh[512 + j]; bb2[s] = bhh[1024 + j];
    } else { b_[s] = 0; u_[s] = 0; }
  }
  gp0 = gi + b_[0] * 1536 + j0 + u_[0];
  gp1 = gi + b_[1] * 1536 + j0 + u_[1];
  if (act2) gp2 = gi + b_[2] * 1536 + j0 + u_[2];
  hs0 = HS + ((long)b_[0] * 64) * 512 + j0 + u_[0];
  hs1 = HS + ((long)b_[1] * 64) * 512 + j0 + u_[1];
  if (act2) hs2 = HS + ((long)b_[2] * 64) * 512 + j0 + u_[2];
  // staging pointers (tid<512): 4 chunks; src advances +1024B/step (t-1 offset)
  const char* sp0 = nullptr; const char* sp1 = nullptr;
  const char* sp2 = nullptr; const char* sp3 = nullptr;
  char* ld0 = nullptr; char* ld1 = nullptr; char* ld2 = nullptr; char* ld3 = nullptr;
  if (tid < 512) {
#pragma unroll
    for (int l = 0; l < 4; ++l) {
      int n = l * 512 + tid;
      int row = n >> 6, i = n & 63;
      const char* sp = (const char*)HS + (long)row * 65536 + i * 16 - 1024;
      char* ld = (char*)Ah + row * 1024 + ((i * 16) ^ ((row & 7) << 4));
      if (l == 0) { sp0 = sp; ld0 = ld; } else if (l == 1) { sp1 = sp; ld1 = ld; }
      else if (l == 2) { sp2 = sp; ld2 = ld; } else { sp3 = sp; ld3 = ld; }
    }
    // t=0: stage h0 from eh (f32 -> bf16) into swizzled Ah
#pragma unroll
    for (int l = 0; l < 4; ++l) {
      int n = l * 512 + tid;
      int row = n >> 6, i = n & 63;
      const float* p = eh + row * 512 + i * 8;
      float4 aa = *reinterpret_cast<const float4*>(p);
      float4 bb = *reinterpret_cast<const float4*>(p + 4);
      u16x8v o8;
      o8[0] = f2bf(aa.x); o8[1] = f2bf(aa.y); o8[2] = f2bf(aa.z); o8[3] = f2bf(aa.w);
      o8[4] = f2bf(bb.x); o8[5] = f2bf(bb.y); o8[6] = f2bf(bb.z); o8[7] = f2bf(bb.w);
      *reinterpret_cast<u16x8v*>((char*)Ah + row * 1024 + ((i * 16) ^ ((row & 7) << 4))) = o8;
    }
  }
  const float K1 = -1.44269504f, K2 = 2.88539009f;
  for (int t = 0; t < 64; ++t) {
    // gi prefetch (independent of h)
    float gr0 = gp0[0], gz0 = gp0[512], gn0 = gp0[1024];
    float gr1 = gp1[0], gz1 = gp1[512], gn1 = gp1[1024];
    float gr2 = 0.f, gz2 = 0.f, gn2 = 0.f;
    if (act2) { gr2 = gp2[0]; gz2 = gp2[512]; gn2 = gp2[1024]; }
    gp0 += 49152; gp1 += 49152; if (act2) gp2 += 49152;
    if (t) {
      if (wave == 0) {
        const unsigned* fp = flags + (lane & 7) * 16;
        unsigned v;
        do {
          asm volatile("global_load_dword %0, %1, off sc0 sc1\n\ts_waitcnt vmcnt(0)"
                       : "=v"(v) : "v"(fp) : "memory");
        } while (!__all((int)(v >= (unsigned)t)));
      }
      __syncthreads();
      if (tid < 512) {
        f32x4 d0, d1, d2, d3;
        asm volatile(
            "global_load_dwordx4 %0, %4, off sc0\n\t"
            "global_load_dwordx4 %1, %5, off sc0\n\t"
            "global_load_dwordx4 %2, %6, off sc0\n\t"
            "global_load_dwordx4 %3, %7, off sc0\n\t"
            "s_waitcnt vmcnt(0)"
            : "=v"(d0), "=v"(d1), "=v"(d2), "=v"(d3)
            : "v"(sp0), "v"(sp1), "v"(sp2), "v"(sp3)
            : "memory");
        *reinterpret_cast<f32x4*>(ld0) = d0;
        *reinterpret_cast<f32x4*>(ld1) = d1;
        *reinterpret_cast<f32x4*>(ld2) = d2;
        *reinterpret_cast<f32x4*>(ld3) = d3;
      }
    }
    if (tid < 512) { sp0 += 1024; sp1 += 1024; sp2 += 1024; sp3 += 1024; }
    __syncthreads();
    // MFMA partials: [32b x 32u x K-half] per wave
    f32x4 acc[2][2] = {};
    int r15 = lane & 15;
    int cbyte = sig * 512 + ((lane >> 4) << 4);
#pragma unroll
    for (int kt = 0; kt < 8; ++kt) {
      bf16x8 a0 = *reinterpret_cast<const bf16x8*>(
          (const char*)Ah + r15 * 1024 + ((kt * 64 + cbyte) ^ ((r15 & 7) << 4)));
      bf16x8 a1 = *reinterpret_cast<const bf16x8*>(
          (const char*)Ah + (16 + r15) * 1024 + ((kt * 64 + cbyte) ^ ((r15 & 7) << 4)));
#pragma unroll
      for (int ut = 0; ut < 2; ++ut) {
        acc[0][ut] = __builtin_amdgcn_mfma_f32_16x16x32_bf16(a0, barr[ut][kt], acc[0][ut], 0, 0, 0);
        acc[1][ut] = __builtin_amdgcn_mfma_f32_16x16x32_bf16(a1, barr[ut][kt], acc[1][ut], 0, 0, 0);
      }
    }
    {
      int ucol = uh * 32 + r15;
      int brow = (lane >> 4) << 2;
#pragma unroll
      for (int q = 0; q < 4; ++q) {
        gh[gate][sig][brow + q][ucol]           = acc[0][0][q];
        gh[gate][sig][brow + q][ucol + 16]      = acc[0][1][q];
        gh[gate][sig][16 + brow + q][ucol]      = acc[1][0][q];
        gh[gate][sig][16 + brow + q][ucol + 16] = acc[1][1][q];
      }
    }
    __syncthreads();
    // elementwise gate math + coherent HS store (HS is the sync medium)
#pragma unroll
    for (int s = 0; s < 3; ++s) {
      if (s == 2 && !act2) break;
      int b = b_[s], u = u_[s];
      float gr = s == 0 ? gr0 : s == 1 ? gr1 : gr2;
      float gz = s == 0 ? gz0 : s == 1 ? gz1 : gz2;
      float gn = s == 0 ? gn0 : s == 1 ? gn1 : gn2;
      float hr = gh[0][0][b][u] + gh[0][1][b][u] + bb0[s];
      float hz = gh[1][0][b][u] + gh[1][1][b][u] + bb1[s];
      float hn = gh[2][0][b][u] + gh[2][1][b][u] + bb2[s];
      float r = 1.f / (1.f + __builtin_amdgcn_exp2f(K1 * (gr + hr)));
      float z = 1.f / (1.f + __builtin_amdgcn_exp2f(K1 * (gz + hz)));
      float x = gn + r * hn;
      float th = 1.f - 2.f / (1.f + __builtin_amdgcn_exp2f(K2 * x));
      float hnew = th + z * (hprev[s] - th);
      hprev[s] = hnew;
      unsigned hb = (unsigned)f2bf(hnew);
      u16* hp = s == 0 ? hs0 : s == 1 ? hs1 : hs2;
      asm volatile("global_store_short %0, %1, off sc0"
                   :: "v"(hp), "v"(hb) : "memory");
    }
    hs0 += 512; hs1 += 512; if (act2) hs2 += 512;
    asm volatile("s_waitcnt vmcnt(0)" ::: "memory");
    __syncthreads();
    if (tid == 0) {
      unsigned ph = (unsigned)(t + 1);
      asm volatile("global_store_dword %0, %1, off sc0 sc1\n\ts_waitcnt vmcnt(0)"
                   :: "v"(flags + g * 16), "v"(ph) : "memory");
    }
  }
  // decoder_hidden output
#pragma unroll
  for (int s = 0; s < 3; ++s) {
    if (s == 2 && !act2) break;
    outH[b_[s] * 512 + j0 + u_[s]] = hprev[s];
  }
}

// ---------------- log_softmax: bf16 logits (aliased in d_out row slot) -> f32 ----------------
extern "C" __global__ void __launch_bounds__(512)
k_lsm_b(const u16* __restrict__ LGbase, float* __restrict__ P) {
  extern __shared__ u16 srb[];
  __shared__ float red[8];
  const u16* LG = LGbase + (long)blockIdx.x * LDC2;   // bf16 copy in own row slot
  float* out = P + (long)blockIdx.x * 32000;
  int tid = threadIdx.x, wave = tid >> 6, lane = tid & 63;
  float mx = -INFINITY;
  for (int i = tid; i < 4000; i += 512) {
    u16x8v v = reinterpret_cast<const u16x8v*>(LG)[i];
    reinterpret_cast<u16x8v*>(srb)[i] = v;
#pragma unroll
    for (int e = 0; e < 8; ++e) mx = fmaxf(mx, bf2f(v[e]));
  }
#pragma unroll
  for (int off = 32; off; off >>= 1) mx = fmaxf(mx, __shfl_down(mx, off, 64));
  if (lane == 0) red[wave] = mx;
  __syncthreads();
  if (tid == 0) {
    float m = red[0];
#pragma unroll
    for (int w = 1; w < 8; ++w) m = fmaxf(m, red[w]);
    red[0] = m;
  }
  __syncthreads();
  mx = red[0];
  __syncthreads();
  float sm = 0.f;
  for (int i = tid; i < 4000; i += 512) {
    u16x8v v = reinterpret_cast<const u16x8v*>(srb)[i];
#pragma unroll
    for (int e = 0; e < 8; ++e) sm += __expf(bf2f(v[e]) - mx);
  }
#pragma unroll
  for (int off = 32; off; off >>= 1) sm += __shfl_down(sm, off, 64);
  if (lane == 0) red[wave] = sm;
  __syncthreads();
  if (tid == 0) {
    float s = 0.f;
#pragma unroll
    for (int w = 0; w < 8; ++w) s += red[w];
    red[0] = mx + __logf(s);
  }
  __syncthreads();
  float L = red[0];
  for (int i = tid; i < 4000; i += 512) {
    u16x8v v = reinterpret_cast<const u16x8v*>(srb)[i];
    float4 o1, o2;
    o1.x = bf2f(v[0]) - L; o1.y = bf2f(v[1]) - L; o1.z = bf2f(v[2]) - L; o1.w = bf2f(v[3]) - L;
    o2.x = bf2f(v[4]) - L; o2.y = bf2f(v[5]) - L; o2.z = bf2f(v[6]) - L; o2.w = bf2f(v[7]) - L;
    reinterpret_cast<float4*>(out + (long)i * 8)[0] = o1;
    reinterpret_cast<float4*>(out + (long)i * 8)[1] = o2;
  }
}

extern "C" void kernel_launch(void* const* d_in, const int* in_sizes, int n_in,
                              void* d_out, int out_size, void* d_ws, size_t ws_size,
                              hipStream_t stream) {
  (void)in_sizes; (void)n_in; (void)out_size;
  const float* enc_hid = (const float*)d_in[1];
  const int*   tgt     = (const int*)d_in[2];
  const float* emb     = (const float*)d_in[3];
  const float* W_ih    = (const float*)d_in[4];
  const float* W_hh    = (const float*)d_in[5];
  const float* b_ih    = (const float*)d_in[6];
  const float* b_hh    = (const float*)d_in[7];
  const float* W_out   = (const float*)d_in[8];
  const float* b_out   = (const float*)d_in[9];
  float* out = (float*)d_out;
  char* ws = (char*)d_ws;
  if (ws_size < (size_t)WS_NEED) return;

  u16* X        = (u16*)(ws + OFF_X);
  u16* Wih      = (u16*)(ws + OFF_WIH);
  u16* Whh      = (u16*)(ws + OFF_WHH);
  u16* Wout     = (u16*)(ws + OFF_WOUT);
  float* gi     = (float*)(ws + OFF_GI);
  u16* HS       = (u16*)(ws + OFF_HS);
  unsigned* flg = (unsigned*)(ws + OFF_FLG);
  unsigned* ev  = (unsigned*)(ws + OFF_EV);
  u16* LG       = (u16*)d_out;   // bf16 logits: row r in first half of row r's f32 slot

  hipFuncSetAttribute(reinterpret_cast<const void*>(k_lsm_b),
                      hipFuncAttributeMaxDynamicSharedMemorySize, 65536);

  k_cast<<<96, 256, 0, stream>>>(W_ih, Wih, 1536 * 256 / 4);
  k_cast<<<192, 256, 0, stream>>>(W_hh, Whh, 1536 * 512 / 4);
  k_cast<<<2048, 256, 0, stream>>>(W_out, Wout, 32000 * 512 / 4);
  k_embed<<<256, 256, 0, stream>>>(emb, tgt, X);
  k_init<<<1, 256, 0, stream>>>(flg, ev);
  k_gemm_t<false><<<(1536 / 128) * (2048 / 128), 256, 0, stream>>>(
      X, Wih, b_ih, gi, nullptr, 2048, 1536, 256, 0);
  k_gru6<<<64, 768, 0, stream>>>(gi, Whh, b_hh, enc_hid, HS, out + BTV, flg, ev);
  k_gemm_t<true><<<(32000 / 128) * (2048 / 128), 256, 0, stream>>>(
      HS, Wout, b_out, nullptr, LG, 2048, 32000, 512, LDC2);
  k_lsm_b<<<2048, 512, 64000, stream>>>(LG, out);
}